// Round 16
// baseline (121.307 us; speedup 1.0000x reference)
//
#include <hip/hip_runtime.h>
#include <cstdint>

typedef __bf16 bf16;
typedef __bf16 bf16x2 __attribute__((ext_vector_type(2)));
typedef __bf16 bf16x4 __attribute__((ext_vector_type(4)));
typedef __bf16 bf16x8 __attribute__((ext_vector_type(8)));
typedef float f32x4 __attribute__((ext_vector_type(4)));

constexpr int S = 2048, D = 1024, H = 16, HD = 64, B = 2;
constexpr size_t TSZ = (size_t)B * H * S * HD;  // 4 Mi elements

__device__ __forceinline__ f32x4 mfma16(bf16x8 a, bf16x8 b, f32x4 c) {
  return __builtin_amdgcn_mfma_f32_16x16x32_bf16(a, b, c, 0, 0, 0);
}

// async global->LDS, 16B per lane. LDS dest = wave-linear (base + lane*16).
__device__ __forceinline__ void gl_lds16(const bf16* g, bf16* s) {
  __builtin_amdgcn_global_load_lds((__attribute__((address_space(1))) void*)g,
                                   (__attribute__((address_space(3))) void*)s,
                                   16, 0, 0);
}

// ---------------------------------------------------------------------------
// prep (merged): blocks 0..2047 convert x fp32->bf16; blocks 2048..3071
// transpose W [K][N] fp32 -> Wt [z][N][K] bf16 via 64x64 LDS tiles.
// ---------------------------------------------------------------------------
__global__ __launch_bounds__(256) void prep_all(const float* __restrict__ x,
                                                const float* __restrict__ W0,
                                                const float* __restrict__ W1,
                                                const float* __restrict__ W2,
                                                const float* __restrict__ W3,
                                                bf16* __restrict__ xb,
                                                bf16* __restrict__ Wt) {
  __shared__ __align__(16) bf16 Lt[64][68];
  const int bid = blockIdx.x, t = threadIdx.x;
  if (bid < 2048) {
    const size_t i = (size_t)bid * 256 + t;
    const float4 a = ((const float4*)x)[2 * i];
    const float4 b = ((const float4*)x)[2 * i + 1];
    bf16x8 o = {(bf16)a.x, (bf16)a.y, (bf16)a.z, (bf16)a.w,
                (bf16)b.x, (bf16)b.y, (bf16)b.z, (bf16)b.w};
    *(bf16x8*)&xb[i * 8] = o;
    return;
  }
  const int r = bid - 2048;
  const int z = r >> 8, rest = r & 255;
  const float* W = z == 0 ? W0 : z == 1 ? W1 : z == 2 ? W2 : W3;
  const int k0 = (rest & 15) * 64, n0 = (rest >> 4) * 64;
  const int tr = t >> 4, tc = (t & 15) * 4;
#pragma unroll
  for (int p = 0; p < 4; ++p) {
    const int rr = 16 * p + tr;
    const float4 v = *(const float4*)&W[(size_t)(k0 + rr) * D + n0 + tc];
    Lt[tc + 0][rr] = (bf16)v.x;
    Lt[tc + 1][rr] = (bf16)v.y;
    Lt[tc + 2][rr] = (bf16)v.z;
    Lt[tc + 3][rr] = (bf16)v.w;
  }
  __syncthreads();
#pragma unroll
  for (int p = 0; p < 4; ++p) {
    const int n = 16 * p + tr;
    const bf16x4 o = *(const bf16x4*)&Lt[n][tc];
    *(bf16x4*)&Wt[((size_t)z * D + n0 + n) * D + k0 + tc] = o;
  }
}

// ---------------------------------------------------------------------------
// bf16 GEMM, m97 structure: BM=128 x BNT tile, BK=64, 4 waves,
// global_load_lds staging with XOR-preswizzled source, swizzled b128 frags.
// MODE 0 (BNT=128): fused QKV. Q,K -> [B,H,S,Dh] bf16. V -> Vp in the
// PERMUTED TILE IMAGE layout (exact byte image of attn's V LDS tile:
// tile (bh, s>>6) is 4096 halfwords; element (kv=s&63, vd=d) lands at
// (vd<<6) | ((vchunk^(vd&7))<<3) | e, vchunk=(kv>>5)<<2 | (kv>>2)&3,
// e=4*((kv>>4)&1) + 2*((kv>>1)&1) + (kv&1) — inverse of the r10-verified
// staging map, so attn can DMA-copy tiles linearly).
// MODE 1 (BNT=64): C fp32 row-major [M][D].
// ---------------------------------------------------------------------------
template <int MODE, int BNT>
__global__ __launch_bounds__(256) void gemm_bt(const bf16* __restrict__ A,
                                               const bf16* __restrict__ Bt,
                                               void* __restrict__ Cp,
                                               bf16* __restrict__ Vp) {
  constexpr int K = 1024;
  constexpr int NI = BNT / 32;            // n-frags per wave (4 or 2)
  __shared__ __align__(16) bf16 As[128 * 64];
  __shared__ __align__(16) bf16 Bs[BNT * 64];

  const int bid = blockIdx.x, nwg = gridDim.x;       // nwg % 8 == 0
  const int lg = (bid & 7) * (nwg >> 3) + (bid >> 3);  // XCD-chunked
  const int bm = (lg & 31) * 128;
  const int bn = (lg >> 5) * BNT;

  const int t = threadIdx.x, l = t & 63, w = t >> 6;
  const int c = l & 15, g = l >> 4, cx = c & 7;
  const int lrow = l >> 3;                  // row within 1KB LDS chunk
  const int srcc = ((l & 7) ^ lrow) << 3;   // pre-swizzled source k-offset
  const int wm = (w >> 1) * 64, wn = (w & 1) * (BNT / 2);

  f32x4 acc[4][NI] = {};

  for (int kt = 0; kt < K / 64; ++kt) {
    const int k0 = kt * 64;
    __syncthreads();  // prior compute done before overwrite
#pragma unroll
    for (int i = 0; i < 4; ++i) {
      const int ci = i * 4 + w;         // 1KB chunk id (16 per 128-row tile)
      const int row = ci * 8 + lrow;    // tile row 0..127
      gl_lds16(A + (size_t)(bm + row) * K + k0 + srcc, As + ci * 512 + l * 8);
    }
#pragma unroll
    for (int i = 0; i < BNT / 32; ++i) {
      const int ci = i * 4 + w;         // BNT/8 chunks of 1KB
      const int row = ci * 8 + lrow;
      gl_lds16(Bt + (size_t)(bn + row) * K + k0 + srcc, Bs + ci * 512 + l * 8);
    }
    __syncthreads();  // drains vmcnt

    bf16x8 af[4][2], bfv[NI][2];
#pragma unroll
    for (int mi = 0; mi < 4; ++mi) {
      const int row = wm + mi * 16 + c;  // row&7 == cx
#pragma unroll
      for (int kh = 0; kh < 2; ++kh)
        af[mi][kh] = *(const bf16x8*)&As[row * 64 + (((kh * 4 + g) ^ cx) << 3)];
    }
#pragma unroll
    for (int ni = 0; ni < NI; ++ni) {
      const int row = wn + ni * 16 + c;
#pragma unroll
      for (int kh = 0; kh < 2; ++kh)
        bfv[ni][kh] = *(const bf16x8*)&Bs[row * 64 + (((kh * 4 + g) ^ cx) << 3)];
    }
#pragma unroll
    for (int mi = 0; mi < 4; ++mi)
#pragma unroll
      for (int ni = 0; ni < NI; ++ni) {
        acc[mi][ni] = mfma16(af[mi][0], bfv[ni][0], acc[mi][ni]);
        acc[mi][ni] = mfma16(af[mi][1], bfv[ni][1], acc[mi][ni]);
      }
  }

  // epilogue: C frag row = 4g+r, col = c (verified mapping)
#pragma unroll
  for (int mi = 0; mi < 4; ++mi)
#pragma unroll
    for (int ni = 0; ni < NI; ++ni)
#pragma unroll
      for (int r = 0; r < 4; ++r) {
        const int m = bm + wm + mi * 16 + 4 * g + r;
        const int n = bn + wn + ni * 16 + c;
        const float v = acc[mi][ni][r];
        if constexpr (MODE == 0) {
          const int which = n >> 10, nn = n & 1023;
          const int h = nn >> 6, d = nn & 63;
          const int bb = m >> 11, s = m & 2047;
          if (which == 2) {
            // permuted tile image for attn V DMA (see header comment)
            const int kv = s & 63;
            const int e = (((kv >> 4) & 1) << 2) | (((kv >> 1) & 1) << 1) | (kv & 1);
            const int vch = ((kv >> 5) << 2) | ((kv >> 2) & 3);
            const int pos = ((vch ^ (d & 7)) << 3) | e;
            Vp[((size_t)((bb * 16 + h) * 32 + (s >> 6)) << 12) + (d << 6) + pos] =
                (bf16)v;
          } else {
            ((bf16*)Cp)[which * TSZ + ((((size_t)bb * H + h) * S + s) << 6) + d] =
                (bf16)v;
          }
        } else {
          ((float*)Cp)[(size_t)m * D + n] = v;
        }
      }
}

// ---------------------------------------------------------------------------
// Flash attention v16 = r11 geometry (512 blocks, 4 waves x 16 q-rows,
// uniform pairs (j,31-j) = 33 iters, in-reg P, direct output) with ALL
// staging via global_load_lds DMA + counted vmcnt(4):
//  - K: gemm-verified pre-swizzled-source DMA (double-buffered).
//  - V: identity-copy DMA of the pre-permuted global tile image (Vp),
//    double-buffered. Zero ds_writes, zero staging register traffic.
// Per iteration: issue 4 DMAs (next tile) -> vmcnt(4) (this tile's 4 DMAs,
// issued last iter, complete) -> barrier -> compute. Last iter issues a
// clamped redundant reload into the unused buffer parity (uniform count).
// LDS 32KB (K dbuf 16K + V dbuf 16K).
// ---------------------------------------------------------------------------
__global__ __launch_bounds__(256, 4) void attn16(const bf16* __restrict__ Q,
                                                 const bf16* __restrict__ Kg,
                                                 const bf16* __restrict__ Vp,
                                                 bf16* __restrict__ O) {
  __shared__ __align__(16) bf16 Ks[2 * 64 * 64];
  __shared__ __align__(16) bf16 Vt[2 * 64 * 64];

  const int bid = blockIdx.x;
  const int bh = bid & 31, j = bid >> 5;          // j in 0..15
  const int t = threadIdx.x, l = t & 63, w = t >> 6;
  const int c = l & 15, g = l >> 4, cx = c & 7;
  const int bb = bh >> 4, h = bh & 15;
  const float SC = 0.18033688011112042f;   // (1/8)*log2(e)
  const float THRS = 44.3614195558365f;    // 8 / SC (defer-max threshold)

  const bf16* Kbase = Kg + (size_t)bh * S * HD;
  const bf16* Vpb = Vp + ((size_t)bh * 32 << 12);  // 32 tiles x 4096 hw

  // DMA maps: 8 chunks of 1KB per 64x64 tile; wave w stages chunks {w, 4+w}
  const int lrow = l >> 3;
  const int srcc = ((l & 7) ^ lrow) << 3;   // K pre-swizzled source offset

  for (int ph = 0; ph < 2; ++ph) {
    const int qt = ph ? (31 - j) : j;
    const int q0 = qt * 64;
    const int qglob = q0 + 16 * w + c;
    const bf16* Qrow = Q + ((size_t)bh * S + qglob) * HD;
    const bf16x8 qf0 = *(const bf16x8*)&Qrow[g * 8];
    const bf16x8 qf1 = *(const bf16x8*)&Qrow[32 + g * 8];

    // ---- phase prologue: tile 0 DMA into buf0 (barrier: phase-1 LDS
    //      reads by other waves must finish before overwrite) ----
    __builtin_amdgcn_s_barrier();
    __builtin_amdgcn_sched_barrier(0);
#pragma unroll
    for (int i = 0; i < 2; ++i) {
      const int ci = w + 4 * i;
      gl_lds16(Kbase + (size_t)(ci * 8 + lrow) * 64 + srcc, Ks + ci * 512 + l * 8);
      gl_lds16(Vpb + ci * 512 + l * 8, Vt + ci * 512 + l * 8);
    }
    __builtin_amdgcn_sched_barrier(0);

    f32x4 oacc[4] = {};
    float mrun = -1e30f, lrun = 0.f;   // lrun: per-lane partial

    for (int kt = 0; kt <= qt; ++kt) {
      // ---- barrier A: all waves done reading previous tile's LDS ----
      __builtin_amdgcn_s_barrier();
      __builtin_amdgcn_sched_barrier(0);

      // ---- issue next tile's 4 DMAs (clamped source, fixed count) ----
      {
        const int ktn = (kt + 1 <= qt) ? kt + 1 : qt;
        const int pb = (kt + 1) & 1;
        const bf16* Kn = Kbase + (size_t)ktn * 64 * HD;
        const bf16* Vn = Vpb + ((size_t)ktn << 12);
#pragma unroll
        for (int i = 0; i < 2; ++i) {
          const int ci = w + 4 * i;
          gl_lds16(Kn + (size_t)(ci * 8 + lrow) * 64 + srcc,
                   Ks + pb * 4096 + ci * 512 + l * 8);
          gl_lds16(Vn + ci * 512 + l * 8, Vt + pb * 4096 + ci * 512 + l * 8);
        }
      }
      __builtin_amdgcn_sched_barrier(0);
      // ---- this tile's DMAs (issued last iter / prologue) complete ----
      asm volatile("s_waitcnt vmcnt(4)" ::: "memory");
      __builtin_amdgcn_s_barrier();
      __builtin_amdgcn_sched_barrier(0);

      const bf16* kbuf = Ks + (kt & 1) * 4096;
      const bf16* vbuf = Vt + (kt & 1) * 4096;

      // ---- S^T = K Q^T ----
      f32x4 st[4];
      __builtin_amdgcn_s_setprio(1);
#pragma unroll
      for (int ct = 0; ct < 4; ++ct) {
        const int krow = ct * 16 + c;  // krow&7 == cx
        const bf16x8 kf0 = *(const bf16x8*)&kbuf[krow * 64 + ((g ^ cx) << 3)];
        const bf16x8 kf1 = *(const bf16x8*)&kbuf[krow * 64 + (((4 + g) ^ cx) << 3)];
        f32x4 z = {};
        z = mfma16(kf0, qf0, z);
        st[ct] = mfma16(kf1, qf1, z);
      }
      __builtin_amdgcn_s_setprio(0);

      if (kt == qt) {  // causal mask, diagonal tile only
#pragma unroll
        for (int ct = 0; ct < 4; ++ct)
#pragma unroll
          for (int r = 0; r < 4; ++r)
            if (kt * 64 + ct * 16 + 4 * g + r > qglob) st[ct][r] = -1e30f;
      }

      // ---- in-lane online softmax: tree max, defer-max rescale ----
      float tm[4];
#pragma unroll
      for (int ct = 0; ct < 4; ++ct)
        tm[ct] = fmaxf(fmaxf(st[ct][0], st[ct][1]), fmaxf(st[ct][2], st[ct][3]));
      float mt = fmaxf(fmaxf(tm[0], tm[1]), fmaxf(tm[2], tm[3]));
      mt = fmaxf(mt, __shfl_xor(mt, 16));
      mt = fmaxf(mt, __shfl_xor(mt, 32));
      if (!__all(mt <= mrun + THRS)) {
        const float mnew = fmaxf(mrun, mt);
        const float fac = __builtin_amdgcn_exp2f((mrun - mnew) * SC);
        lrun *= fac;
#pragma unroll
        for (int ct = 0; ct < 4; ++ct)
#pragma unroll
          for (int r = 0; r < 4; ++r) oacc[ct][r] *= fac;
        mrun = mnew;
      }
      float p[4][4];
      float sq[4];
#pragma unroll
      for (int ct = 0; ct < 4; ++ct) {
#pragma unroll
        for (int r = 0; r < 4; ++r)
          p[ct][r] = __builtin_amdgcn_exp2f((st[ct][r] - mrun) * SC);
        sq[ct] = (p[ct][0] + p[ct][1]) + (p[ct][2] + p[ct][3]);
      }
      lrun += (sq[0] + sq[1]) + (sq[2] + sq[3]);

      // ---- P in-register (slot k=8g+jj <-> kv 32h+16(jj>=4)+4g+(jj&3)) ----
      const bf16x8 pa0 = {(bf16)p[0][0], (bf16)p[0][1], (bf16)p[0][2], (bf16)p[0][3],
                          (bf16)p[1][0], (bf16)p[1][1], (bf16)p[1][2], (bf16)p[1][3]};
      const bf16x8 pa1 = {(bf16)p[2][0], (bf16)p[2][1], (bf16)p[2][2], (bf16)p[2][3],
                          (bf16)p[3][0], (bf16)p[3][1], (bf16)p[3][2], (bf16)p[3][3]};

      // ---- O^T += V^T P^T (V^T tile image already kv-permuted) ----
      __builtin_amdgcn_s_setprio(1);
#pragma unroll
      for (int ct = 0; ct < 4; ++ct) {
        const int vrow = ct * 16 + c;
        const bf16x8 vt0 = *(const bf16x8*)&vbuf[vrow * 64 + ((g ^ cx) << 3)];
        const bf16x8 vt1 = *(const bf16x8*)&vbuf[vrow * 64 + (((4 + g) ^ cx) << 3)];
        oacc[ct] = mfma16(vt0, pa0, oacc[ct]);
        oacc[ct] = mfma16(vt1, pa1, oacc[ct]);
      }
      __builtin_amdgcn_s_setprio(0);
    }

    // ---- epilogue: reduce l, normalize, direct bf16 store to [B,S,D] ----
    float lt = lrun;
    lt += __shfl_xor(lt, 16);
    lt += __shfl_xor(lt, 32);
    const float inv = 1.f / lt;
    bf16* Orow = O + ((size_t)bb * S + qglob) * D + h * 64;
#pragma unroll
    for (int ct = 0; ct < 4; ++ct)
#pragma unroll
      for (int pr = 0; pr < 2; ++pr) {
        bf16x2 pk = {(bf16)(oacc[ct][2 * pr] * inv),
                     (bf16)(oacc[ct][2 * pr + 1] * inv)};
        *(bf16x2*)&Orow[ct * 16 + 4 * g + 2 * pr] = pk;
      }
  }
}

// ---------------------------------------------------------------------------
extern "C" void kernel_launch(void* const* d_in, const int* in_sizes, int n_in,
                              void* d_out, int out_size, void* d_ws, size_t ws_size,
                              hipStream_t stream) {
  const float* x  = (const float*)d_in[0];
  const float* Wq = (const float*)d_in[1];
  const float* Wk = (const float*)d_in[2];
  const float* Wv = (const float*)d_in[3];
  const float* Wo = (const float*)d_in[4];
  float* out = (float*)d_out;

  bf16* xb  = (bf16*)d_ws;                       // 4Mi  (8 MB)
  bf16* Wt  = xb + (size_t)B * S * D;            // 4Mi  (8 MB) [4][1024][1024]
  bf16* QKV = Wt + (size_t)4 * D * D;            // 12Mi (24 MB) Q,K used
  bf16* Ab  = QKV + 3 * TSZ;                     // 4Mi  (8 MB) [B*S][D]
  bf16* Vp  = Ab + TSZ;                          // 4Mi  (8 MB) permuted V tiles

  prep_all<<<3072, 256, 0, stream>>>(x, Wq, Wk, Wv, Wo, xb, Wt);
  gemm_bt<0, 128><<<768, 256, 0, stream>>>(xb, Wt, QKV, Vp);         // fused QKV
  attn16<<<512, 256, 0, stream>>>(QKV, QKV + TSZ, Vp, Ab);
  gemm_bt<1, 64><<<512, 256, 0, stream>>>(Ab, Wt + (size_t)3 * D * D, out, nullptr);
}

// Round 17
// 104.602 us; speedup vs baseline: 1.1597x; 1.1597x over previous
//
#include <hip/hip_runtime.h>
#include <cstdint>

typedef __bf16 bf16;
typedef __bf16 bf16x2 __attribute__((ext_vector_type(2)));
typedef __bf16 bf16x4 __attribute__((ext_vector_type(4)));
typedef __bf16 bf16x8 __attribute__((ext_vector_type(8)));
typedef float f32x4 __attribute__((ext_vector_type(4)));

constexpr int S = 2048, D = 1024, H = 16, HD = 64, B = 2;
constexpr size_t TSZ = (size_t)B * H * S * HD;  // 4 Mi elements

__device__ __forceinline__ f32x4 mfma16(bf16x8 a, bf16x8 b, f32x4 c) {
  return __builtin_amdgcn_mfma_f32_16x16x32_bf16(a, b, c, 0, 0, 0);
}

// async global->LDS, 16B per lane. LDS dest = wave-linear (base + lane*16).
__device__ __forceinline__ void gl_lds16(const bf16* g, bf16* s) {
  __builtin_amdgcn_global_load_lds((__attribute__((address_space(1))) void*)g,
                                   (__attribute__((address_space(3))) void*)s,
                                   16, 0, 0);
}

// ---------------------------------------------------------------------------
// prep (merged): blocks 0..2047 convert x fp32->bf16; blocks 2048..3071
// transpose W [K][N] fp32 -> Wt [z][N][K] bf16 via 64x64 LDS tiles.
// ---------------------------------------------------------------------------
__global__ __launch_bounds__(256) void prep_all(const float* __restrict__ x,
                                                const float* __restrict__ W0,
                                                const float* __restrict__ W1,
                                                const float* __restrict__ W2,
                                                const float* __restrict__ W3,
                                                bf16* __restrict__ xb,
                                                bf16* __restrict__ Wt) {
  __shared__ __align__(16) bf16 Lt[64][68];
  const int bid = blockIdx.x, t = threadIdx.x;
  if (bid < 2048) {
    const size_t i = (size_t)bid * 256 + t;
    const float4 a = ((const float4*)x)[2 * i];
    const float4 b = ((const float4*)x)[2 * i + 1];
    bf16x8 o = {(bf16)a.x, (bf16)a.y, (bf16)a.z, (bf16)a.w,
                (bf16)b.x, (bf16)b.y, (bf16)b.z, (bf16)b.w};
    *(bf16x8*)&xb[i * 8] = o;
    return;
  }
  const int r = bid - 2048;
  const int z = r >> 8, rest = r & 255;
  const float* W = z == 0 ? W0 : z == 1 ? W1 : z == 2 ? W2 : W3;
  const int k0 = (rest & 15) * 64, n0 = (rest >> 4) * 64;
  const int tr = t >> 4, tc = (t & 15) * 4;
#pragma unroll
  for (int p = 0; p < 4; ++p) {
    const int rr = 16 * p + tr;
    const float4 v = *(const float4*)&W[(size_t)(k0 + rr) * D + n0 + tc];
    Lt[tc + 0][rr] = (bf16)v.x;
    Lt[tc + 1][rr] = (bf16)v.y;
    Lt[tc + 2][rr] = (bf16)v.z;
    Lt[tc + 3][rr] = (bf16)v.w;
  }
  __syncthreads();
#pragma unroll
  for (int p = 0; p < 4; ++p) {
    const int n = 16 * p + tr;
    const bf16x4 o = *(const bf16x4*)&Lt[n][tc];
    *(bf16x4*)&Wt[((size_t)z * D + n0 + n) * D + k0 + tc] = o;
  }
}

// ---------------------------------------------------------------------------
// bf16 GEMM, m97 structure (r11-verified form): BM=128 x BNT, BK=64, 4 waves,
// global_load_lds staging with XOR-preswizzled source, swizzled b128 frags.
// MODE 0 (BNT=128): C bf16 scattered to [3][B,H,S,Dh] (fused QKV).
// MODE 1 (BNT=64):  C fp32 row-major [M][D].
// ---------------------------------------------------------------------------
template <int MODE, int BNT>
__global__ __launch_bounds__(256) void gemm_bt(const bf16* __restrict__ A,
                                               const bf16* __restrict__ Bt,
                                               void* __restrict__ Cp) {
  constexpr int K = 1024;
  constexpr int NI = BNT / 32;            // n-frags per wave (4 or 2)
  __shared__ __align__(16) bf16 As[128 * 64];
  __shared__ __align__(16) bf16 Bs[BNT * 64];

  const int bid = blockIdx.x, nwg = gridDim.x;       // nwg % 8 == 0
  const int lg = (bid & 7) * (nwg >> 3) + (bid >> 3);  // XCD-chunked
  const int bm = (lg & 31) * 128;
  const int bn = (lg >> 5) * BNT;

  const int t = threadIdx.x, l = t & 63, w = t >> 6;
  const int c = l & 15, g = l >> 4, cx = c & 7;
  const int lrow = l >> 3;                  // row within 1KB LDS chunk
  const int srcc = ((l & 7) ^ lrow) << 3;   // pre-swizzled source k-offset
  const int wm = (w >> 1) * 64, wn = (w & 1) * (BNT / 2);

  f32x4 acc[4][NI] = {};

  for (int kt = 0; kt < K / 64; ++kt) {
    const int k0 = kt * 64;
    __syncthreads();  // prior compute done before overwrite
#pragma unroll
    for (int i = 0; i < 4; ++i) {
      const int ci = i * 4 + w;         // 1KB chunk id (16 per 128-row tile)
      const int row = ci * 8 + lrow;    // tile row 0..127
      gl_lds16(A + (size_t)(bm + row) * K + k0 + srcc, As + ci * 512 + l * 8);
    }
#pragma unroll
    for (int i = 0; i < BNT / 32; ++i) {
      const int ci = i * 4 + w;         // BNT/8 chunks of 1KB
      const int row = ci * 8 + lrow;
      gl_lds16(Bt + (size_t)(bn + row) * K + k0 + srcc, Bs + ci * 512 + l * 8);
    }
    __syncthreads();  // drains vmcnt

    bf16x8 af[4][2], bfv[NI][2];
#pragma unroll
    for (int mi = 0; mi < 4; ++mi) {
      const int row = wm + mi * 16 + c;  // row&7 == cx
#pragma unroll
      for (int kh = 0; kh < 2; ++kh)
        af[mi][kh] = *(const bf16x8*)&As[row * 64 + (((kh * 4 + g) ^ cx) << 3)];
    }
#pragma unroll
    for (int ni = 0; ni < NI; ++ni) {
      const int row = wn + ni * 16 + c;
#pragma unroll
      for (int kh = 0; kh < 2; ++kh)
        bfv[ni][kh] = *(const bf16x8*)&Bs[row * 64 + (((kh * 4 + g) ^ cx) << 3)];
    }
#pragma unroll
    for (int mi = 0; mi < 4; ++mi)
#pragma unroll
      for (int ni = 0; ni < NI; ++ni) {
        acc[mi][ni] = mfma16(af[mi][0], bfv[ni][0], acc[mi][ni]);
        acc[mi][ni] = mfma16(af[mi][1], bfv[ni][1], acc[mi][ni]);
      }
  }

  // epilogue: C frag row = 4g+r, col = c (verified mapping)
#pragma unroll
  for (int mi = 0; mi < 4; ++mi)
#pragma unroll
    for (int ni = 0; ni < NI; ++ni)
#pragma unroll
      for (int r = 0; r < 4; ++r) {
        const int m = bm + wm + mi * 16 + 4 * g + r;
        const int n = bn + wn + ni * 16 + c;
        const float v = acc[mi][ni][r];
        if constexpr (MODE == 0) {
          const int which = n >> 10, nn = n & 1023;
          const int h = nn >> 6, d = nn & 63;
          const int bb = m >> 11, s = m & 2047;
          ((bf16*)Cp)[which * TSZ + ((((size_t)bb * H + h) * S + s) << 6) + d] =
              (bf16)v;
        } else {
          ((float*)Cp)[(size_t)m * D + n] = v;
        }
      }
}

// ---------------------------------------------------------------------------
// vperm: V [B,H,S,Dh] -> Vp permuted tile images (8KB per 64-kv tile), via
// LDS bounce. LDS write = r10-verified staging formula (byte-identical to the
// mapping that passed correctness in r16); LDS read + global store = linear,
// fully coalesced. One block per tile; 1024 blocks.
// ---------------------------------------------------------------------------
__global__ __launch_bounds__(256) void vperm(const bf16* __restrict__ V,
                                             bf16* __restrict__ Vp) {
  __shared__ __align__(16) bf16 Vt[64 * 64];
  const int tile = blockIdx.x;            // bh*32 + (s>>6)
  const int t = threadIdx.x;
  const bf16* Vsrc = V + ((size_t)tile << 12);  // natural [kv][64]
  const int p2 = t & 31, dgv = t >> 5;
  const int hv = p2 >> 4, gv = (p2 >> 1) & 3;
  const int jv = ((p2 >> 3) & 1) * 4 + (p2 & 1) * 2;
  const int vchunk = (hv << 2) | gv;
  const bf16x8 va0 = *(const bf16x8*)&Vsrc[(2 * p2) * 64 + dgv * 8];
  const bf16x8 va1 = *(const bf16x8*)&Vsrc[(2 * p2 + 1) * 64 + dgv * 8];
#pragma unroll
  for (int i = 0; i < 8; ++i) {
    bf16x2 pr2 = {va0[i], va1[i]};
    *(bf16x2*)&Vt[(8 * dgv + i) * 64 + ((vchunk ^ i) << 3) + jv] = pr2;
  }
  __syncthreads();
  bf16* dst = Vp + ((size_t)tile << 12);
#pragma unroll
  for (int r = 0; r < 2; ++r)
    *(bf16x8*)&dst[r * 2048 + t * 8] = *(const bf16x8*)&Vt[r * 2048 + t * 8];
}

// ---------------------------------------------------------------------------
// Flash attention v17 = attn16's all-DMA inner loop (K pre-swizzled DMA +
// V identity DMA of Vp tile image, double-buffered, counted vmcnt(4), zero
// ds_writes) + r15's 48-item fine split (1536 blocks, max 16 iters,
// 5 blocks/CU LDS-limited with backfill) + r14 bf16-normalized partials.
// Items/bh: e<16: qt=31-e half0 [0,ceil((qt+1)/2)); e<32: qt=47-e half1;
// e>=32: qt=47-e single. Splits are qt>=16 only -> rows >= 1024 -> merge2.
// LDS 32KB (K dbuf 16K + V dbuf 16K).
// ---------------------------------------------------------------------------
__global__ __launch_bounds__(256, 4) void attn17(const bf16* __restrict__ Q,
                                                 const bf16* __restrict__ Kg,
                                                 const bf16* __restrict__ Vp,
                                                 bf16* __restrict__ Ab,
                                                 bf16* __restrict__ Op,
                                                 float* __restrict__ ML) {
  __shared__ __align__(16) bf16 Ks[2 * 64 * 64];
  __shared__ __align__(16) bf16 Vt[2 * 64 * 64];

  const int bid = blockIdx.x;
  const int e = bid >> 5, bh = bid & 31;   // same-bh blocks share an XCD
  int qt, kvA, kvB, half;
  bool split;
  if (e < 16)      { qt = 31 - e; half = 0; split = true;  kvA = 0; kvB = (qt + 2) >> 1; }
  else if (e < 32) { qt = 47 - e; half = 1; split = true;  kvA = (qt + 2) >> 1; kvB = qt + 1; }
  else             { qt = 47 - e; half = 0; split = false; kvA = 0; kvB = qt + 1; }

  const int t = threadIdx.x, l = t & 63, w = t >> 6;
  const int c = l & 15, g = l >> 4, cx = c & 7;
  const int bb = bh >> 4, h = bh & 15;
  const float SC = 0.18033688011112042f;   // (1/8)*log2(e)
  const float THRS = 44.3614195558365f;    // 8 / SC (defer-max threshold)

  const bf16* Kbase = Kg + (size_t)bh * S * HD;
  const bf16* Vpb = Vp + ((size_t)bh * 32 << 12);  // 32 tiles x 4096 hw

  const int qglob = qt * 64 + 16 * w + c;
  const bf16* Qrow = Q + ((size_t)bh * S + qglob) * HD;
  const bf16x8 qf0 = *(const bf16x8*)&Qrow[g * 8];
  const bf16x8 qf1 = *(const bf16x8*)&Qrow[32 + g * 8];

  // DMA maps: 8 chunks of 1KB per tile; wave w stages chunks {w, 4+w}
  const int lrow = l >> 3;
  const int srcc = ((l & 7) ^ lrow) << 3;   // K pre-swizzled source offset

  // ---- prologue: tile kvA DMA into parity kvA&1 ----
  {
    const bf16* K0 = Kbase + (size_t)kvA * 64 * HD;
    const bf16* V0 = Vpb + ((size_t)kvA << 12);
    const int pb = kvA & 1;
#pragma unroll
    for (int i = 0; i < 2; ++i) {
      const int ci = w + 4 * i;
      gl_lds16(K0 + (size_t)(ci * 8 + lrow) * 64 + srcc,
               Ks + pb * 4096 + ci * 512 + l * 8);
      gl_lds16(V0 + ci * 512 + l * 8, Vt + pb * 4096 + ci * 512 + l * 8);
    }
  }
  __builtin_amdgcn_sched_barrier(0);

  f32x4 oacc[4] = {};
  float mrun = -1e30f, lrun = 0.f;   // lrun: per-lane partial

  for (int kt = kvA; kt < kvB; ++kt) {
    // ---- barrier A: all waves done reading the other buffer ----
    __builtin_amdgcn_s_barrier();
    __builtin_amdgcn_sched_barrier(0);

    // ---- issue next tile's 4 DMAs (clamped source, fixed count) ----
    {
      const int ktn = (kt + 1 < kvB) ? kt + 1 : kvB - 1;
      const int pb = (kt + 1) & 1;
      const bf16* Kn = Kbase + (size_t)ktn * 64 * HD;
      const bf16* Vn = Vpb + ((size_t)ktn << 12);
#pragma unroll
      for (int i = 0; i < 2; ++i) {
        const int ci = w + 4 * i;
        gl_lds16(Kn + (size_t)(ci * 8 + lrow) * 64 + srcc,
                 Ks + pb * 4096 + ci * 512 + l * 8);
        gl_lds16(Vn + ci * 512 + l * 8, Vt + pb * 4096 + ci * 512 + l * 8);
      }
    }
    __builtin_amdgcn_sched_barrier(0);
    // ---- this tile's DMAs (issued last iter / prologue) complete ----
    asm volatile("s_waitcnt vmcnt(4)" ::: "memory");
    __builtin_amdgcn_s_barrier();
    __builtin_amdgcn_sched_barrier(0);

    const bf16* kbuf = Ks + (kt & 1) * 4096;
    const bf16* vbuf = Vt + (kt & 1) * 4096;

    // ---- S^T = K Q^T ----
    f32x4 st[4];
    __builtin_amdgcn_s_setprio(1);
#pragma unroll
    for (int ct = 0; ct < 4; ++ct) {
      const int krow = ct * 16 + c;  // krow&7 == cx
      const bf16x8 kf0 = *(const bf16x8*)&kbuf[krow * 64 + ((g ^ cx) << 3)];
      const bf16x8 kf1 = *(const bf16x8*)&kbuf[krow * 64 + (((4 + g) ^ cx) << 3)];
      f32x4 z = {};
      z = mfma16(kf0, qf0, z);
      st[ct] = mfma16(kf1, qf1, z);
    }
    __builtin_amdgcn_s_setprio(0);

    if (kt == qt) {  // causal mask, diagonal tile only
#pragma unroll
      for (int ct = 0; ct < 4; ++ct)
#pragma unroll
        for (int r = 0; r < 4; ++r)
          if (kt * 64 + ct * 16 + 4 * g + r > qglob) st[ct][r] = -1e30f;
    }

    // ---- in-lane online softmax: tree max, defer-max rescale ----
    float tm[4];
#pragma unroll
    for (int ct = 0; ct < 4; ++ct)
      tm[ct] = fmaxf(fmaxf(st[ct][0], st[ct][1]), fmaxf(st[ct][2], st[ct][3]));
    float mt = fmaxf(fmaxf(tm[0], tm[1]), fmaxf(tm[2], tm[3]));
    mt = fmaxf(mt, __shfl_xor(mt, 16));
    mt = fmaxf(mt, __shfl_xor(mt, 32));
    if (!__all(mt <= mrun + THRS)) {
      const float mnew = fmaxf(mrun, mt);
      const float fac = __builtin_amdgcn_exp2f((mrun - mnew) * SC);
      lrun *= fac;
#pragma unroll
      for (int ct = 0; ct < 4; ++ct)
#pragma unroll
        for (int r = 0; r < 4; ++r) oacc[ct][r] *= fac;
      mrun = mnew;
    }
    float p[4][4];
    float sq[4];
#pragma unroll
    for (int ct = 0; ct < 4; ++ct) {
#pragma unroll
      for (int r = 0; r < 4; ++r)
        p[ct][r] = __builtin_amdgcn_exp2f((st[ct][r] - mrun) * SC);
      sq[ct] = (p[ct][0] + p[ct][1]) + (p[ct][2] + p[ct][3]);
    }
    lrun += (sq[0] + sq[1]) + (sq[2] + sq[3]);

    // ---- P in-register (slot k=8g+jj <-> kv 32h+16(jj>=4)+4g+(jj&3)) ----
    const bf16x8 pa0 = {(bf16)p[0][0], (bf16)p[0][1], (bf16)p[0][2], (bf16)p[0][3],
                        (bf16)p[1][0], (bf16)p[1][1], (bf16)p[1][2], (bf16)p[1][3]};
    const bf16x8 pa1 = {(bf16)p[2][0], (bf16)p[2][1], (bf16)p[2][2], (bf16)p[2][3],
                        (bf16)p[3][0], (bf16)p[3][1], (bf16)p[3][2], (bf16)p[3][3]};

    // ---- O^T += V^T P^T (V^T tile image already kv-permuted) ----
    __builtin_amdgcn_s_setprio(1);
#pragma unroll
    for (int ct = 0; ct < 4; ++ct) {
      const int vrow = ct * 16 + c;
      const bf16x8 vt0 = *(const bf16x8*)&vbuf[vrow * 64 + ((g ^ cx) << 3)];
      const bf16x8 vt1 = *(const bf16x8*)&vbuf[vrow * 64 + (((4 + g) ^ cx) << 3)];
      oacc[ct] = mfma16(vt0, pa0, oacc[ct]);
      oacc[ct] = mfma16(vt1, pa1, oacc[ct]);
    }
    __builtin_amdgcn_s_setprio(0);
  }

  // ---- epilogue: reduce l, store direct or as normalized partial ----
  float lt = lrun;
  lt += __shfl_xor(lt, 16);
  lt += __shfl_xor(lt, 32);
  const float inv = 1.f / lt;

  if (!split) {
    bf16* Orow = Ab + ((size_t)bb * S + qglob) * D + h * 64;
#pragma unroll
    for (int ct = 0; ct < 4; ++ct)
#pragma unroll
      for (int pr = 0; pr < 2; ++pr) {
        bf16x2 pk = {(bf16)(oacc[ct][2 * pr] * inv),
                     (bf16)(oacc[ct][2 * pr + 1] * inv)};
        *(bf16x2*)&Orow[ct * 16 + 4 * g + 2 * pr] = pk;
      }
  } else {
    // split items have qt >= 16 -> qglob >= 1024
    const size_t ra = ((size_t)bh * 1024 + (qglob - 1024)) * 2 + half;
    bf16* Pa = Op + ra * 64;
#pragma unroll
    for (int ct = 0; ct < 4; ++ct)
#pragma unroll
      for (int pr = 0; pr < 2; ++pr) {
        bf16x2 pk = {(bf16)(oacc[ct][2 * pr] * inv),
                     (bf16)(oacc[ct][2 * pr + 1] * inv)};
        *(bf16x2*)&Pa[ct * 16 + 4 * g + 2 * pr] = pk;
      }
    if (g == 0) { ML[ra * 2] = mrun; ML[ra * 2 + 1] = lt; }
  }
}

// ---------------------------------------------------------------------------
// Merge split-kv partials (rows 1024..2047 of every bh) -> Ab bf16.
// One wave per row; partials are self-normalized bf16 + (m, l) f32.
// ---------------------------------------------------------------------------
__global__ __launch_bounds__(256) void attn_merge2(const bf16* __restrict__ Op,
                                                   const float* __restrict__ ML,
                                                   bf16* __restrict__ Ab) {
  const float SC = 0.18033688011112042f;
  const int rid = blockIdx.x * 4 + (threadIdx.x >> 6);  // 0..32767
  const int lane = threadIdx.x & 63;
  const int bh = rid >> 10, rw = rid & 1023;
  const size_t r2 = (size_t)rid * 2;
  const float m0 = ML[(r2 + 0) * 2], l0 = ML[(r2 + 0) * 2 + 1];
  const float m1 = ML[(r2 + 1) * 2], l1 = ML[(r2 + 1) * 2 + 1];
  const float o0 = (float)Op[(r2 + 0) * 64 + lane];
  const float o1 = (float)Op[(r2 + 1) * 64 + lane];
  const float mn = fmaxf(m0, m1);
  const float w0 = l0 * exp2f((m0 - mn) * SC);
  const float w1 = l1 * exp2f((m1 - mn) * SC);
  const float o = (o0 * w0 + o1 * w1) / (w0 + w1);
  const int bb = bh >> 4, h = bh & 15, s = 1024 + rw;
  Ab[((size_t)bb * S + s) * D + h * 64 + lane] = (bf16)o;
}

// ---------------------------------------------------------------------------
extern "C" void kernel_launch(void* const* d_in, const int* in_sizes, int n_in,
                              void* d_out, int out_size, void* d_ws, size_t ws_size,
                              hipStream_t stream) {
  const float* x  = (const float*)d_in[0];
  const float* Wq = (const float*)d_in[1];
  const float* Wk = (const float*)d_in[2];
  const float* Wv = (const float*)d_in[3];
  const float* Wo = (const float*)d_in[4];
  float* out = (float*)d_out;

  bf16* xb  = (bf16*)d_ws;                       // 4Mi  (8 MB)
  bf16* Wt  = xb + (size_t)B * S * D;            // 4Mi  (8 MB) [4][1024][1024]
  bf16* QKV = Wt + (size_t)4 * D * D;            // 12Mi (24 MB) [3][B,H,S,Dh]
  bf16* Ab  = QKV + 3 * TSZ;                     // 4Mi  (8 MB) [B*S][D]
  bf16* Vp  = Ab + TSZ;                          // 4Mi  (8 MB) permuted V tiles
  bf16* Op  = Vp + TSZ;                          // 4Mi  (8 MB) split partials
  float* ML = (float*)(Op + (size_t)32 * 1024 * 2 * 64);  // 128 K f32

  prep_all<<<3072, 256, 0, stream>>>(x, Wq, Wk, Wv, Wo, xb, Wt);
  gemm_bt<0, 128><<<768, 256, 0, stream>>>(xb, Wt, QKV);             // fused QKV
  vperm<<<1024, 256, 0, stream>>>(QKV + 2 * TSZ, Vp);
  attn17<<<1536, 256, 0, stream>>>(QKV, QKV + TSZ, Vp, Ab, Op, ML);
  attn_merge2<<<8192, 256, 0, stream>>>(Op, ML, Ab);
  gemm_bt<1, 64><<<512, 256, 0, stream>>>(Ab, Wt + (size_t)3 * D * D, out);
}

// Round 18
// 96.204 us; speedup vs baseline: 1.2609x; 1.0873x over previous
//
#include <hip/hip_runtime.h>
#include <cstdint>

typedef __bf16 bf16;
typedef __bf16 bf16x2 __attribute__((ext_vector_type(2)));
typedef __bf16 bf16x4 __attribute__((ext_vector_type(4)));
typedef __bf16 bf16x8 __attribute__((ext_vector_type(8)));
typedef float f32x4 __attribute__((ext_vector_type(4)));

constexpr int S = 2048, D = 1024, H = 16, HD = 64, B = 2;
constexpr size_t TSZ = (size_t)B * H * S * HD;  // 4 Mi elements

__device__ __forceinline__ f32x4 mfma16(bf16x8 a, bf16x8 b, f32x4 c) {
  return __builtin_amdgcn_mfma_f32_16x16x32_bf16(a, b, c, 0, 0, 0);
}

// async global->LDS, 16B per lane. LDS dest = wave-linear (base + lane*16).
__device__ __forceinline__ void gl_lds16(const bf16* g, bf16* s) {
  __builtin_amdgcn_global_load_lds((__attribute__((address_space(1))) void*)g,
                                   (__attribute__((address_space(3))) void*)s,
                                   16, 0, 0);
}

// ---------------------------------------------------------------------------
// prep (merged): blocks 0..2047 convert x fp32->bf16; blocks 2048..3071
// transpose W [K][N] fp32 -> Wt [z][N][K] bf16 via 64x64 LDS tiles.
// ---------------------------------------------------------------------------
__global__ __launch_bounds__(256) void prep_all(const float* __restrict__ x,
                                                const float* __restrict__ W0,
                                                const float* __restrict__ W1,
                                                const float* __restrict__ W2,
                                                const float* __restrict__ W3,
                                                bf16* __restrict__ xb,
                                                bf16* __restrict__ Wt) {
  __shared__ __align__(16) bf16 Lt[64][68];
  const int bid = blockIdx.x, t = threadIdx.x;
  if (bid < 2048) {
    const size_t i = (size_t)bid * 256 + t;
    const float4 a = ((const float4*)x)[2 * i];
    const float4 b = ((const float4*)x)[2 * i + 1];
    bf16x8 o = {(bf16)a.x, (bf16)a.y, (bf16)a.z, (bf16)a.w,
                (bf16)b.x, (bf16)b.y, (bf16)b.z, (bf16)b.w};
    *(bf16x8*)&xb[i * 8] = o;
    return;
  }
  const int r = bid - 2048;
  const int z = r >> 8, rest = r & 255;
  const float* W = z == 0 ? W0 : z == 1 ? W1 : z == 2 ? W2 : W3;
  const int k0 = (rest & 15) * 64, n0 = (rest >> 4) * 64;
  const int tr = t >> 4, tc = (t & 15) * 4;
#pragma unroll
  for (int p = 0; p < 4; ++p) {
    const int rr = 16 * p + tr;
    const float4 v = *(const float4*)&W[(size_t)(k0 + rr) * D + n0 + tc];
    Lt[tc + 0][rr] = (bf16)v.x;
    Lt[tc + 1][rr] = (bf16)v.y;
    Lt[tc + 2][rr] = (bf16)v.z;
    Lt[tc + 3][rr] = (bf16)v.w;
  }
  __syncthreads();
#pragma unroll
  for (int p = 0; p < 4; ++p) {
    const int n = 16 * p + tr;
    const bf16x4 o = *(const bf16x4*)&Lt[n][tc];
    *(bf16x4*)&Wt[((size_t)z * D + n0 + n) * D + k0 + tc] = o;
  }
}

// ---------------------------------------------------------------------------
// bf16 GEMM, m97 structure: BM=128 x BNT, BK=64, 4 waves, global_load_lds
// staging with XOR-preswizzled source, swizzled b128 frags.
// MODE 0 (BNT=128): fused QKV. Q,K scattered to [B,H,S,Dh] bf16. V blocks
// (bn>=2048) bounce through the (reused) 32KB LDS to emit permuted tile
// images into Vp (r16-verified mapping; coalesced 16B stores both sides).
// MODE 1 (BNT=64): C fp32 row-major [M][D].
// ---------------------------------------------------------------------------
template <int MODE, int BNT>
__global__ __launch_bounds__(256) void gemm_bt(const bf16* __restrict__ A,
                                               const bf16* __restrict__ Bt,
                                               void* __restrict__ Cp,
                                               bf16* __restrict__ Vp) {
  constexpr int K = 1024;
  constexpr int NI = BNT / 32;            // n-frags per wave (4 or 2)
  __shared__ __align__(16) bf16 Sh[(128 + BNT) * 64];
  bf16* As = Sh;
  bf16* Bs = Sh + 128 * 64;

  const int bid = blockIdx.x, nwg = gridDim.x;       // nwg % 8 == 0
  const int lg = (bid & 7) * (nwg >> 3) + (bid >> 3);  // XCD-chunked
  const int bm = (lg & 31) * 128;
  const int bn = (lg >> 5) * BNT;

  const int t = threadIdx.x, l = t & 63, w = t >> 6;
  const int c = l & 15, g = l >> 4, cx = c & 7;
  const int lrow = l >> 3;                  // row within 1KB LDS chunk
  const int srcc = ((l & 7) ^ lrow) << 3;   // pre-swizzled source k-offset
  const int wm = (w >> 1) * 64, wn = (w & 1) * (BNT / 2);

  f32x4 acc[4][NI] = {};

  for (int kt = 0; kt < K / 64; ++kt) {
    const int k0 = kt * 64;
    __syncthreads();  // prior compute done before overwrite
#pragma unroll
    for (int i = 0; i < 4; ++i) {
      const int ci = i * 4 + w;         // 1KB chunk id (16 per 128-row tile)
      const int row = ci * 8 + lrow;    // tile row 0..127
      gl_lds16(A + (size_t)(bm + row) * K + k0 + srcc, As + ci * 512 + l * 8);
    }
#pragma unroll
    for (int i = 0; i < BNT / 32; ++i) {
      const int ci = i * 4 + w;         // BNT/8 chunks of 1KB
      const int row = ci * 8 + lrow;
      gl_lds16(Bt + (size_t)(bn + row) * K + k0 + srcc, Bs + ci * 512 + l * 8);
    }
    __syncthreads();  // drains vmcnt

    bf16x8 af[4][2], bfv[NI][2];
#pragma unroll
    for (int mi = 0; mi < 4; ++mi) {
      const int row = wm + mi * 16 + c;  // row&7 == cx
#pragma unroll
      for (int kh = 0; kh < 2; ++kh)
        af[mi][kh] = *(const bf16x8*)&As[row * 64 + (((kh * 4 + g) ^ cx) << 3)];
    }
#pragma unroll
    for (int ni = 0; ni < NI; ++ni) {
      const int row = wn + ni * 16 + c;
#pragma unroll
      for (int kh = 0; kh < 2; ++kh)
        bfv[ni][kh] = *(const bf16x8*)&Bs[row * 64 + (((kh * 4 + g) ^ cx) << 3)];
    }
#pragma unroll
    for (int mi = 0; mi < 4; ++mi)
#pragma unroll
      for (int ni = 0; ni < NI; ++ni) {
        acc[mi][ni] = mfma16(af[mi][0], bfv[ni][0], acc[mi][ni]);
        acc[mi][ni] = mfma16(af[mi][1], bfv[ni][1], acc[mi][ni]);
      }
  }

  // ---- epilogue (C frag row = 4g+r, col = c; verified mapping) ----
  if (MODE == 0 && bn >= 2048) {
    // V block: bounce through LDS to emit permuted tile images (32KB = 4 tiles)
    __syncthreads();  // all waves done with final fragment reads
#pragma unroll
    for (int mi = 0; mi < 4; ++mi)
#pragma unroll
      for (int ni = 0; ni < NI; ++ni)
#pragma unroll
        for (int r = 0; r < 4; ++r) {
          const int m = bm + wm + mi * 16 + 4 * g + r;
          const int n = bn + wn + ni * 16 + c;
          const int kv = m & 63, d = n & 63;
          const int e = (((kv >> 4) & 1) << 2) | (((kv >> 1) & 1) << 1) | (kv & 1);
          const int vch = ((kv >> 5) << 2) | ((kv >> 2) & 3);
          const int tloc = (((m >> 6) & 1) << 1) | ((n >> 6) & 1);
          Sh[tloc * 4096 + (d << 6) + ((vch ^ (d & 7)) << 3) + e] =
              (bf16)acc[mi][ni][r];
        }
    __syncthreads();
    const int bb2 = bm >> 11, hb = (bn & 1023) >> 6, st0 = (bm & 2047) >> 6;
#pragma unroll
    for (int tl = 0; tl < 4; ++tl) {
      const size_t gt = (size_t)(bb2 * 16 + hb + (tl & 1)) * 32 + st0 + (tl >> 1);
      bf16* dst = Vp + (gt << 12);
      *(bf16x8*)&dst[t * 8] = *(const bf16x8*)&Sh[tl * 4096 + t * 8];
      *(bf16x8*)&dst[2048 + t * 8] = *(const bf16x8*)&Sh[tl * 4096 + 2048 + t * 8];
    }
    return;
  }
#pragma unroll
  for (int mi = 0; mi < 4; ++mi)
#pragma unroll
    for (int ni = 0; ni < NI; ++ni)
#pragma unroll
      for (int r = 0; r < 4; ++r) {
        const int m = bm + wm + mi * 16 + 4 * g + r;
        const int n = bn + wn + ni * 16 + c;
        const float v = acc[mi][ni][r];
        if constexpr (MODE == 0) {
          const int which = n >> 10, nn = n & 1023;
          const int h = nn >> 6, d = nn & 63;
          const int bb = m >> 11, s = m & 2047;
          ((bf16*)Cp)[which * TSZ + ((((size_t)bb * H + h) * S + s) << 6) + d] =
              (bf16)v;
        } else {
          ((float*)Cp)[(size_t)m * D + n] = v;
        }
      }
}

// ---------------------------------------------------------------------------
// Flash attention v18 = attn17's all-DMA inner loop (K pre-swizzled DMA +
// V identity DMA of Vp tile image, double-buffered, counted vmcnt(4), zero
// ds_writes) on r11's UNIFORM PAIRING geometry: 512 blocks = 32 bh x 16
// pairs; block runs q-tiles (j, 31-j) sequentially = exactly 33 iterations.
// Direct bf16 output; no split, no partials, no merge kernel.
// Last iteration of each phase waits vmcnt(0) (no redundant DMAs, no
// cross-phase DMA hazard). LDS 32KB (K dbuf 16K + V dbuf 16K).
// ---------------------------------------------------------------------------
__global__ __launch_bounds__(256, 4) void attn18(const bf16* __restrict__ Q,
                                                 const bf16* __restrict__ Kg,
                                                 const bf16* __restrict__ Vp,
                                                 bf16* __restrict__ O) {
  __shared__ __align__(16) bf16 Ks[2 * 64 * 64];
  __shared__ __align__(16) bf16 Vt[2 * 64 * 64];

  const int bid = blockIdx.x;
  const int bh = bid & 31, j = bid >> 5;          // j in 0..15
  const int t = threadIdx.x, l = t & 63, w = t >> 6;
  const int c = l & 15, g = l >> 4, cx = c & 7;
  const int bb = bh >> 4, h = bh & 15;
  const float SC = 0.18033688011112042f;   // (1/8)*log2(e)
  const float THRS = 44.3614195558365f;    // 8 / SC (defer-max threshold)

  const bf16* Kbase = Kg + (size_t)bh * S * HD;
  const bf16* Vpb = Vp + ((size_t)bh * 32 << 12);  // 32 tiles x 4096 hw

  // DMA maps: 8 chunks of 1KB per tile; wave w stages chunks {w, 4+w}
  const int lrow = l >> 3;
  const int srcc = ((l & 7) ^ lrow) << 3;   // K pre-swizzled source offset

  for (int ph = 0; ph < 2; ++ph) {
    const int qt = ph ? (31 - j) : j;
    const int qglob = qt * 64 + 16 * w + c;
    const bf16* Qrow = Q + ((size_t)bh * S + qglob) * HD;
    const bf16x8 qf0 = *(const bf16x8*)&Qrow[g * 8];
    const bf16x8 qf1 = *(const bf16x8*)&Qrow[32 + g * 8];

    // ---- phase prologue: protect buffers, then tile-0 DMA into buf0 ----
    __builtin_amdgcn_s_barrier();
    __builtin_amdgcn_sched_barrier(0);
#pragma unroll
    for (int i = 0; i < 2; ++i) {
      const int ci = w + 4 * i;
      gl_lds16(Kbase + (size_t)(ci * 8 + lrow) * 64 + srcc, Ks + ci * 512 + l * 8);
      gl_lds16(Vpb + ci * 512 + l * 8, Vt + ci * 512 + l * 8);
    }
    __builtin_amdgcn_sched_barrier(0);

    f32x4 oacc[4] = {};
    float mrun = -1e30f, lrun = 0.f;   // lrun: per-lane partial

    for (int kt = 0; kt <= qt; ++kt) {
      // ---- barrier A: all waves done reading the target buffer ----
      __builtin_amdgcn_s_barrier();
      __builtin_amdgcn_sched_barrier(0);

      if (kt < qt) {
        // ---- issue next tile's 4 DMAs into the other buffer ----
        const int pb = (kt + 1) & 1;
        const bf16* Kn = Kbase + (size_t)(kt + 1) * 64 * HD;
        const bf16* Vn = Vpb + ((size_t)(kt + 1) << 12);
#pragma unroll
        for (int i = 0; i < 2; ++i) {
          const int ci = w + 4 * i;
          gl_lds16(Kn + (size_t)(ci * 8 + lrow) * 64 + srcc,
                   Ks + pb * 4096 + ci * 512 + l * 8);
          gl_lds16(Vn + ci * 512 + l * 8, Vt + pb * 4096 + ci * 512 + l * 8);
        }
        __builtin_amdgcn_sched_barrier(0);
        asm volatile("s_waitcnt vmcnt(4)" ::: "memory");
      } else {
        asm volatile("s_waitcnt vmcnt(0)" ::: "memory");
      }
      __builtin_amdgcn_s_barrier();   // barrier B: tile kt complete (all waves)
      __builtin_amdgcn_sched_barrier(0);

      const bf16* kbuf = Ks + (kt & 1) * 4096;
      const bf16* vbuf = Vt + (kt & 1) * 4096;

      // ---- S^T = K Q^T ----
      f32x4 st[4];
      __builtin_amdgcn_s_setprio(1);
#pragma unroll
      for (int ct = 0; ct < 4; ++ct) {
        const int krow = ct * 16 + c;  // krow&7 == cx
        const bf16x8 kf0 = *(const bf16x8*)&kbuf[krow * 64 + ((g ^ cx) << 3)];
        const bf16x8 kf1 = *(const bf16x8*)&kbuf[krow * 64 + (((4 + g) ^ cx) << 3)];
        f32x4 z = {};
        z = mfma16(kf0, qf0, z);
        st[ct] = mfma16(kf1, qf1, z);
      }
      __builtin_amdgcn_s_setprio(0);

      if (kt == qt) {  // causal mask, diagonal tile only
#pragma unroll
        for (int ct = 0; ct < 4; ++ct)
#pragma unroll
          for (int r = 0; r < 4; ++r)
            if (kt * 64 + ct * 16 + 4 * g + r > qglob) st[ct][r] = -1e30f;
      }

      // ---- in-lane online softmax: tree max, defer-max rescale ----
      float tm[4];
#pragma unroll
      for (int ct = 0; ct < 4; ++ct)
        tm[ct] = fmaxf(fmaxf(st[ct][0], st[ct][1]), fmaxf(st[ct][2], st[ct][3]));
      float mt = fmaxf(fmaxf(tm[0], tm[1]), fmaxf(tm[2], tm[3]));
      mt = fmaxf(mt, __shfl_xor(mt, 16));
      mt = fmaxf(mt, __shfl_xor(mt, 32));
      if (!__all(mt <= mrun + THRS)) {
        const float mnew = fmaxf(mrun, mt);
        const float fac = __builtin_amdgcn_exp2f((mrun - mnew) * SC);
        lrun *= fac;
#pragma unroll
        for (int ct = 0; ct < 4; ++ct)
#pragma unroll
          for (int r = 0; r < 4; ++r) oacc[ct][r] *= fac;
        mrun = mnew;
      }
      float p[4][4];
      float sq[4];
#pragma unroll
      for (int ct = 0; ct < 4; ++ct) {
#pragma unroll
        for (int r = 0; r < 4; ++r)
          p[ct][r] = __builtin_amdgcn_exp2f((st[ct][r] - mrun) * SC);
        sq[ct] = (p[ct][0] + p[ct][1]) + (p[ct][2] + p[ct][3]);
      }
      lrun += (sq[0] + sq[1]) + (sq[2] + sq[3]);

      // ---- P in-register (slot k=8g+jj <-> kv 32h+16(jj>=4)+4g+(jj&3)) ----
      const bf16x8 pa0 = {(bf16)p[0][0], (bf16)p[0][1], (bf16)p[0][2], (bf16)p[0][3],
                          (bf16)p[1][0], (bf16)p[1][1], (bf16)p[1][2], (bf16)p[1][3]};
      const bf16x8 pa1 = {(bf16)p[2][0], (bf16)p[2][1], (bf16)p[2][2], (bf16)p[2][3],
                          (bf16)p[3][0], (bf16)p[3][1], (bf16)p[3][2], (bf16)p[3][3]};

      // ---- O^T += V^T P^T (V^T tile image already kv-permuted) ----
      __builtin_amdgcn_s_setprio(1);
#pragma unroll
      for (int ct = 0; ct < 4; ++ct) {
        const int vrow = ct * 16 + c;
        const bf16x8 vt0 = *(const bf16x8*)&vbuf[vrow * 64 + ((g ^ cx) << 3)];
        const bf16x8 vt1 = *(const bf16x8*)&vbuf[vrow * 64 + (((4 + g) ^ cx) << 3)];
        oacc[ct] = mfma16(vt0, pa0, oacc[ct]);
        oacc[ct] = mfma16(vt1, pa1, oacc[ct]);
      }
      __builtin_amdgcn_s_setprio(0);
    }

    // ---- epilogue: reduce l, normalize, direct bf16 store to [B,S,D] ----
    float lt = lrun;
    lt += __shfl_xor(lt, 16);
    lt += __shfl_xor(lt, 32);
    const float inv = 1.f / lt;
    bf16* Orow = O + ((size_t)bb * S + qglob) * D + h * 64;
#pragma unroll
    for (int ct = 0; ct < 4; ++ct)
#pragma unroll
      for (int pr = 0; pr < 2; ++pr) {
        bf16x2 pk = {(bf16)(oacc[ct][2 * pr] * inv),
                     (bf16)(oacc[ct][2 * pr + 1] * inv)};
        *(bf16x2*)&Orow[ct * 16 + 4 * g + 2 * pr] = pk;
      }
  }
}

// ---------------------------------------------------------------------------
extern "C" void kernel_launch(void* const* d_in, const int* in_sizes, int n_in,
                              void* d_out, int out_size, void* d_ws, size_t ws_size,
                              hipStream_t stream) {
  const float* x  = (const float*)d_in[0];
  const float* Wq = (const float*)d_in[1];
  const float* Wk = (const float*)d_in[2];
  const float* Wv = (const float*)d_in[3];
  const float* Wo = (const float*)d_in[4];
  float* out = (float*)d_out;

  bf16* xb  = (bf16*)d_ws;                       // 4Mi  (8 MB)
  bf16* Wt  = xb + (size_t)B * S * D;            // 4Mi  (8 MB) [4][1024][1024]
  bf16* QKV = Wt + (size_t)4 * D * D;            // 12Mi (24 MB) Q,K used
  bf16* Ab  = QKV + 3 * TSZ;                     // 4Mi  (8 MB) [B*S][D]
  bf16* Vp  = Ab + TSZ;                          // 4Mi  (8 MB) permuted V tiles

  prep_all<<<3072, 256, 0, stream>>>(x, Wq, Wk, Wv, Wo, xb, Wt);
  gemm_bt<0, 128><<<768, 256, 0, stream>>>(xb, Wt, QKV, Vp);         // fused QKV
  attn18<<<512, 256, 0, stream>>>(QKV, QKV + TSZ, Vp, Ab);
  gemm_bt<1, 64><<<512, 256, 0, stream>>>(Ab, Wt + (size_t)3 * D * D, out, nullptr);
}

// Round 19
// 96.052 us; speedup vs baseline: 1.2629x; 1.0016x over previous
//
#include <hip/hip_runtime.h>
#include <cstdint>

typedef __bf16 bf16;
typedef __bf16 bf16x2 __attribute__((ext_vector_type(2)));
typedef __bf16 bf16x4 __attribute__((ext_vector_type(4)));
typedef __bf16 bf16x8 __attribute__((ext_vector_type(8)));
typedef float f32x4 __attribute__((ext_vector_type(4)));

constexpr int S = 2048, D = 1024, H = 16, HD = 64, B = 2;
constexpr size_t TSZ = (size_t)B * H * S * HD;  // 4 Mi elements

__device__ __forceinline__ f32x4 mfma16(bf16x8 a, bf16x8 b, f32x4 c) {
  return __builtin_amdgcn_mfma_f32_16x16x32_bf16(a, b, c, 0, 0, 0);
}

// async global->LDS, 16B per lane. LDS dest = wave-linear (base + lane*16).
__device__ __forceinline__ void gl_lds16(const bf16* g, bf16* s) {
  __builtin_amdgcn_global_load_lds((__attribute__((address_space(1))) void*)g,
                                   (__attribute__((address_space(3))) void*)s,
                                   16, 0, 0);
}

// ---------------------------------------------------------------------------
// prep (merged): blocks 0..2047 convert x fp32->bf16; blocks 2048..3071
// transpose W [K][N] fp32 -> Wt [z][N][K] bf16 via 64x64 LDS tiles.
// ---------------------------------------------------------------------------
__global__ __launch_bounds__(256) void prep_all(const float* __restrict__ x,
                                                const float* __restrict__ W0,
                                                const float* __restrict__ W1,
                                                const float* __restrict__ W2,
                                                const float* __restrict__ W3,
                                                bf16* __restrict__ xb,
                                                bf16* __restrict__ Wt) {
  __shared__ __align__(16) bf16 Lt[64][68];
  const int bid = blockIdx.x, t = threadIdx.x;
  if (bid < 2048) {
    const size_t i = (size_t)bid * 256 + t;
    const float4 a = ((const float4*)x)[2 * i];
    const float4 b = ((const float4*)x)[2 * i + 1];
    bf16x8 o = {(bf16)a.x, (bf16)a.y, (bf16)a.z, (bf16)a.w,
                (bf16)b.x, (bf16)b.y, (bf16)b.z, (bf16)b.w};
    *(bf16x8*)&xb[i * 8] = o;
    return;
  }
  const int r = bid - 2048;
  const int z = r >> 8, rest = r & 255;
  const float* W = z == 0 ? W0 : z == 1 ? W1 : z == 2 ? W2 : W3;
  const int k0 = (rest & 15) * 64, n0 = (rest >> 4) * 64;
  const int tr = t >> 4, tc = (t & 15) * 4;
#pragma unroll
  for (int p = 0; p < 4; ++p) {
    const int rr = 16 * p + tr;
    const float4 v = *(const float4*)&W[(size_t)(k0 + rr) * D + n0 + tc];
    Lt[tc + 0][rr] = (bf16)v.x;
    Lt[tc + 1][rr] = (bf16)v.y;
    Lt[tc + 2][rr] = (bf16)v.z;
    Lt[tc + 3][rr] = (bf16)v.w;
  }
  __syncthreads();
#pragma unroll
  for (int p = 0; p < 4; ++p) {
    const int n = 16 * p + tr;
    const bf16x4 o = *(const bf16x4*)&Lt[n][tc];
    *(bf16x4*)&Wt[((size_t)z * D + n0 + n) * D + k0 + tc] = o;
  }
}

// ---------------------------------------------------------------------------
// bf16 GEMM, m97 structure: BM=128 x BNT, BK=64, 4 waves, global_load_lds
// staging with XOR-preswizzled source, swizzled b128 frags.
// MODE 0 (BNT=128): fused QKV. Q,K scattered to [B,H,S,Dh] bf16. V blocks
// (bn>=2048) bounce through the (reused) 32KB LDS to emit permuted tile
// images into Vp (r16-verified mapping; coalesced 16B stores both sides).
// MODE 1 (BNT=64): C fp32 row-major [M][D].
// ---------------------------------------------------------------------------
template <int MODE, int BNT>
__global__ __launch_bounds__(256) void gemm_bt(const bf16* __restrict__ A,
                                               const bf16* __restrict__ Bt,
                                               void* __restrict__ Cp,
                                               bf16* __restrict__ Vp) {
  constexpr int K = 1024;
  constexpr int NI = BNT / 32;            // n-frags per wave (4 or 2)
  __shared__ __align__(16) bf16 Sh[(128 + BNT) * 64];
  bf16* As = Sh;
  bf16* Bs = Sh + 128 * 64;

  const int bid = blockIdx.x, nwg = gridDim.x;       // nwg % 8 == 0
  const int lg = (bid & 7) * (nwg >> 3) + (bid >> 3);  // XCD-chunked
  const int bm = (lg & 31) * 128;
  const int bn = (lg >> 5) * BNT;

  const int t = threadIdx.x, l = t & 63, w = t >> 6;
  const int c = l & 15, g = l >> 4, cx = c & 7;
  const int lrow = l >> 3;                  // row within 1KB LDS chunk
  const int srcc = ((l & 7) ^ lrow) << 3;   // pre-swizzled source k-offset
  const int wm = (w >> 1) * 64, wn = (w & 1) * (BNT / 2);

  f32x4 acc[4][NI] = {};

  for (int kt = 0; kt < K / 64; ++kt) {
    const int k0 = kt * 64;
    __syncthreads();  // prior compute done before overwrite
#pragma unroll
    for (int i = 0; i < 4; ++i) {
      const int ci = i * 4 + w;         // 1KB chunk id (16 per 128-row tile)
      const int row = ci * 8 + lrow;    // tile row 0..127
      gl_lds16(A + (size_t)(bm + row) * K + k0 + srcc, As + ci * 512 + l * 8);
    }
#pragma unroll
    for (int i = 0; i < BNT / 32; ++i) {
      const int ci = i * 4 + w;         // BNT/8 chunks of 1KB
      const int row = ci * 8 + lrow;
      gl_lds16(Bt + (size_t)(bn + row) * K + k0 + srcc, Bs + ci * 512 + l * 8);
    }
    __syncthreads();  // drains vmcnt

    bf16x8 af[4][2], bfv[NI][2];
#pragma unroll
    for (int mi = 0; mi < 4; ++mi) {
      const int row = wm + mi * 16 + c;  // row&7 == cx
#pragma unroll
      for (int kh = 0; kh < 2; ++kh)
        af[mi][kh] = *(const bf16x8*)&As[row * 64 + (((kh * 4 + g) ^ cx) << 3)];
    }
#pragma unroll
    for (int ni = 0; ni < NI; ++ni) {
      const int row = wn + ni * 16 + c;
#pragma unroll
      for (int kh = 0; kh < 2; ++kh)
        bfv[ni][kh] = *(const bf16x8*)&Bs[row * 64 + (((kh * 4 + g) ^ cx) << 3)];
    }
#pragma unroll
    for (int mi = 0; mi < 4; ++mi)
#pragma unroll
      for (int ni = 0; ni < NI; ++ni) {
        acc[mi][ni] = mfma16(af[mi][0], bfv[ni][0], acc[mi][ni]);
        acc[mi][ni] = mfma16(af[mi][1], bfv[ni][1], acc[mi][ni]);
      }
  }

  // ---- epilogue (C frag row = 4g+r, col = c; verified mapping) ----
  if (MODE == 0 && bn >= 2048) {
    // V block: bounce through LDS to emit permuted tile images (32KB = 4 tiles)
    __syncthreads();  // all waves done with final fragment reads
#pragma unroll
    for (int mi = 0; mi < 4; ++mi)
#pragma unroll
      for (int ni = 0; ni < NI; ++ni)
#pragma unroll
        for (int r = 0; r < 4; ++r) {
          const int m = bm + wm + mi * 16 + 4 * g + r;
          const int n = bn + wn + ni * 16 + c;
          const int kv = m & 63, d = n & 63;
          const int e = (((kv >> 4) & 1) << 2) | (((kv >> 1) & 1) << 1) | (kv & 1);
          const int vch = ((kv >> 5) << 2) | ((kv >> 2) & 3);
          const int tloc = (((m >> 6) & 1) << 1) | ((n >> 6) & 1);
          Sh[tloc * 4096 + (d << 6) + ((vch ^ (d & 7)) << 3) + e] =
              (bf16)acc[mi][ni][r];
        }
    __syncthreads();
    const int bb2 = bm >> 11, hb = (bn & 1023) >> 6, st0 = (bm & 2047) >> 6;
#pragma unroll
    for (int tl = 0; tl < 4; ++tl) {
      const size_t gt = (size_t)(bb2 * 16 + hb + (tl & 1)) * 32 + st0 + (tl >> 1);
      bf16* dst = Vp + (gt << 12);
      *(bf16x8*)&dst[t * 8] = *(const bf16x8*)&Sh[tl * 4096 + t * 8];
      *(bf16x8*)&dst[2048 + t * 8] = *(const bf16x8*)&Sh[tl * 4096 + 2048 + t * 8];
    }
    return;
  }
#pragma unroll
  for (int mi = 0; mi < 4; ++mi)
#pragma unroll
    for (int ni = 0; ni < NI; ++ni)
#pragma unroll
      for (int r = 0; r < 4; ++r) {
        const int m = bm + wm + mi * 16 + 4 * g + r;
        const int n = bn + wn + ni * 16 + c;
        const float v = acc[mi][ni][r];
        if constexpr (MODE == 0) {
          const int which = n >> 10, nn = n & 1023;
          const int h = nn >> 6, d = nn & 63;
          const int bb = m >> 11, s = m & 2047;
          ((bf16*)Cp)[which * TSZ + ((((size_t)bb * H + h) * S + s) << 6) + d] =
              (bf16)v;
        } else {
          ((float*)Cp)[(size_t)m * D + n] = v;
        }
      }
}

// ---------------------------------------------------------------------------
// Flash attention v19 = r18 (all-DMA staging, uniform pairing, direct out)
// with ONE BARRIER PER ITERATION. With double-buffered LDS the sequence
//   vmcnt(0) -> s_barrier -> issue(kt+1 into parity^1) -> compute(kt)
// is sufficient: at the barrier every wave has (a) finished compute kt-1 =
// last reads of parity^1 and (b) drained its tile-kt DMAs (issued a full
// iteration earlier, so vmcnt(0) is near-free). The single barrier thus
// certifies both "tile kt fully in LDS" and "parity^1 reusable"; issuing
// kt+1 after it is write-after-read safe. Halves barrier convergences.
// ---------------------------------------------------------------------------
__global__ __launch_bounds__(256, 4) void attn19(const bf16* __restrict__ Q,
                                                 const bf16* __restrict__ Kg,
                                                 const bf16* __restrict__ Vp,
                                                 bf16* __restrict__ O) {
  __shared__ __align__(16) bf16 Ks[2 * 64 * 64];
  __shared__ __align__(16) bf16 Vt[2 * 64 * 64];

  const int bid = blockIdx.x;
  const int bh = bid & 31, j = bid >> 5;          // j in 0..15
  const int t = threadIdx.x, l = t & 63, w = t >> 6;
  const int c = l & 15, g = l >> 4, cx = c & 7;
  const int bb = bh >> 4, h = bh & 15;
  const float SC = 0.18033688011112042f;   // (1/8)*log2(e)
  const float THRS = 44.3614195558365f;    // 8 / SC (defer-max threshold)

  const bf16* Kbase = Kg + (size_t)bh * S * HD;
  const bf16* Vpb = Vp + ((size_t)bh * 32 << 12);  // 32 tiles x 4096 hw

  // DMA maps: 8 chunks of 1KB per tile; wave w stages chunks {w, 4+w}
  const int lrow = l >> 3;
  const int srcc = ((l & 7) ^ lrow) << 3;   // K pre-swizzled source offset

  for (int ph = 0; ph < 2; ++ph) {
    const int qt = ph ? (31 - j) : j;
    const int qglob = qt * 64 + 16 * w + c;
    const bf16* Qrow = Q + ((size_t)bh * S + qglob) * HD;
    const bf16x8 qf0 = *(const bf16x8*)&Qrow[g * 8];
    const bf16x8 qf1 = *(const bf16x8*)&Qrow[32 + g * 8];

    // ---- phase prologue: protect buffers from previous phase's readers,
    //      then tile-0 DMA into buf0 (issued after barrier => safe) ----
    __builtin_amdgcn_s_barrier();
    __builtin_amdgcn_sched_barrier(0);
#pragma unroll
    for (int i = 0; i < 2; ++i) {
      const int ci = w + 4 * i;
      gl_lds16(Kbase + (size_t)(ci * 8 + lrow) * 64 + srcc, Ks + ci * 512 + l * 8);
      gl_lds16(Vpb + ci * 512 + l * 8, Vt + ci * 512 + l * 8);
    }
    __builtin_amdgcn_sched_barrier(0);

    f32x4 oacc[4] = {};
    float mrun = -1e30f, lrun = 0.f;   // lrun: per-lane partial

    for (int kt = 0; kt <= qt; ++kt) {
      // ---- single sync point: my kt DMAs drained, then all-wave barrier ----
      asm volatile("s_waitcnt vmcnt(0)" ::: "memory");
      __builtin_amdgcn_s_barrier();
      __builtin_amdgcn_sched_barrier(0);

      // ---- issue next tile's 4 DMAs into the other buffer (post-barrier:
      //      all waves are done reading it) ----
      if (kt < qt) {
        const int pb = (kt + 1) & 1;
        const bf16* Kn = Kbase + (size_t)(kt + 1) * 64 * HD;
        const bf16* Vn = Vpb + ((size_t)(kt + 1) << 12);
#pragma unroll
        for (int i = 0; i < 2; ++i) {
          const int ci = w + 4 * i;
          gl_lds16(Kn + (size_t)(ci * 8 + lrow) * 64 + srcc,
                   Ks + pb * 4096 + ci * 512 + l * 8);
          gl_lds16(Vn + ci * 512 + l * 8, Vt + pb * 4096 + ci * 512 + l * 8);
        }
        __builtin_amdgcn_sched_barrier(0);
      }

      const bf16* kbuf = Ks + (kt & 1) * 4096;
      const bf16* vbuf = Vt + (kt & 1) * 4096;

      // ---- S^T = K Q^T ----
      f32x4 st[4];
      __builtin_amdgcn_s_setprio(1);
#pragma unroll
      for (int ct = 0; ct < 4; ++ct) {
        const int krow = ct * 16 + c;  // krow&7 == cx
        const bf16x8 kf0 = *(const bf16x8*)&kbuf[krow * 64 + ((g ^ cx) << 3)];
        const bf16x8 kf1 = *(const bf16x8*)&kbuf[krow * 64 + (((4 + g) ^ cx) << 3)];
        f32x4 z = {};
        z = mfma16(kf0, qf0, z);
        st[ct] = mfma16(kf1, qf1, z);
      }
      __builtin_amdgcn_s_setprio(0);

      if (kt == qt) {  // causal mask, diagonal tile only
#pragma unroll
        for (int ct = 0; ct < 4; ++ct)
#pragma unroll
          for (int r = 0; r < 4; ++r)
            if (kt * 64 + ct * 16 + 4 * g + r > qglob) st[ct][r] = -1e30f;
      }

      // ---- in-lane online softmax: tree max, defer-max rescale ----
      float tm[4];
#pragma unroll
      for (int ct = 0; ct < 4; ++ct)
        tm[ct] = fmaxf(fmaxf(st[ct][0], st[ct][1]), fmaxf(st[ct][2], st[ct][3]));
      float mt = fmaxf(fmaxf(tm[0], tm[1]), fmaxf(tm[2], tm[3]));
      mt = fmaxf(mt, __shfl_xor(mt, 16));
      mt = fmaxf(mt, __shfl_xor(mt, 32));
      if (!__all(mt <= mrun + THRS)) {
        const float mnew = fmaxf(mrun, mt);
        const float fac = __builtin_amdgcn_exp2f((mrun - mnew) * SC);
        lrun *= fac;
#pragma unroll
        for (int ct = 0; ct < 4; ++ct)
#pragma unroll
          for (int r = 0; r < 4; ++r) oacc[ct][r] *= fac;
        mrun = mnew;
      }
      float p[4][4];
      float sq[4];
#pragma unroll
      for (int ct = 0; ct < 4; ++ct) {
#pragma unroll
        for (int r = 0; r < 4; ++r)
          p[ct][r] = __builtin_amdgcn_exp2f((st[ct][r] - mrun) * SC);
        sq[ct] = (p[ct][0] + p[ct][1]) + (p[ct][2] + p[ct][3]);
      }
      lrun += (sq[0] + sq[1]) + (sq[2] + sq[3]);

      // ---- P in-register (slot k=8g+jj <-> kv 32h+16(jj>=4)+4g+(jj&3)) ----
      const bf16x8 pa0 = {(bf16)p[0][0], (bf16)p[0][1], (bf16)p[0][2], (bf16)p[0][3],
                          (bf16)p[1][0], (bf16)p[1][1], (bf16)p[1][2], (bf16)p[1][3]};
      const bf16x8 pa1 = {(bf16)p[2][0], (bf16)p[2][1], (bf16)p[2][2], (bf16)p[2][3],
                          (bf16)p[3][0], (bf16)p[3][1], (bf16)p[3][2], (bf16)p[3][3]};

      // ---- O^T += V^T P^T (V^T tile image already kv-permuted) ----
      __builtin_amdgcn_s_setprio(1);
#pragma unroll
      for (int ct = 0; ct < 4; ++ct) {
        const int vrow = ct * 16 + c;
        const bf16x8 vt0 = *(const bf16x8*)&vbuf[vrow * 64 + ((g ^ cx) << 3)];
        const bf16x8 vt1 = *(const bf16x8*)&vbuf[vrow * 64 + (((4 + g) ^ cx) << 3)];
        oacc[ct] = mfma16(vt0, pa0, oacc[ct]);
        oacc[ct] = mfma16(vt1, pa1, oacc[ct]);
      }
      __builtin_amdgcn_s_setprio(0);
    }

    // ---- epilogue: reduce l, normalize, direct bf16 store to [B,S,D] ----
    float lt = lrun;
    lt += __shfl_xor(lt, 16);
    lt += __shfl_xor(lt, 32);
    const float inv = 1.f / lt;
    bf16* Orow = O + ((size_t)bb * S + qglob) * D + h * 64;
#pragma unroll
    for (int ct = 0; ct < 4; ++ct)
#pragma unroll
      for (int pr = 0; pr < 2; ++pr) {
        bf16x2 pk = {(bf16)(oacc[ct][2 * pr] * inv),
                     (bf16)(oacc[ct][2 * pr + 1] * inv)};
        *(bf16x2*)&Orow[ct * 16 + 4 * g + 2 * pr] = pk;
      }
  }
}

// ---------------------------------------------------------------------------
extern "C" void kernel_launch(void* const* d_in, const int* in_sizes, int n_in,
                              void* d_out, int out_size, void* d_ws, size_t ws_size,
                              hipStream_t stream) {
  const float* x  = (const float*)d_in[0];
  const float* Wq = (const float*)d_in[1];
  const float* Wk = (const float*)d_in[2];
  const float* Wv = (const float*)d_in[3];
  const float* Wo = (const float*)d_in[4];
  float* out = (float*)d_out;

  bf16* xb  = (bf16*)d_ws;                       // 4Mi  (8 MB)
  bf16* Wt  = xb + (size_t)B * S * D;            // 4Mi  (8 MB) [4][1024][1024]
  bf16* QKV = Wt + (size_t)4 * D * D;            // 12Mi (24 MB) Q,K used
  bf16* Ab  = QKV + 3 * TSZ;                     // 4Mi  (8 MB) [B*S][D]
  bf16* Vp  = Ab + TSZ;                          // 4Mi  (8 MB) permuted V tiles

  prep_all<<<3072, 256, 0, stream>>>(x, Wq, Wk, Wv, Wo, xb, Wt);
  gemm_bt<0, 128><<<768, 256, 0, stream>>>(xb, Wt, QKV, Vp);         // fused QKV
  attn19<<<512, 256, 0, stream>>>(QKV, QKV + TSZ, Vp, Ab);
  gemm_bt<1, 64><<<512, 256, 0, stream>>>(Ab, Wt + (size_t)3 * D * D, out, nullptr);
}

// Round 20
// 94.097 us; speedup vs baseline: 1.2892x; 1.0208x over previous
//
#include <hip/hip_runtime.h>
#include <cstdint>

typedef __bf16 bf16;
typedef __bf16 bf16x2 __attribute__((ext_vector_type(2)));
typedef __bf16 bf16x4 __attribute__((ext_vector_type(4)));
typedef __bf16 bf16x8 __attribute__((ext_vector_type(8)));
typedef float f32x4 __attribute__((ext_vector_type(4)));

constexpr int S = 2048, D = 1024, H = 16, HD = 64, B = 2;
constexpr size_t TSZ = (size_t)B * H * S * HD;  // 4 Mi elements

__device__ __forceinline__ f32x4 mfma16(bf16x8 a, bf16x8 b, f32x4 c) {
  return __builtin_amdgcn_mfma_f32_16x16x32_bf16(a, b, c, 0, 0, 0);
}

// async global->LDS, 16B per lane. LDS dest = wave-linear (base + lane*16).
__device__ __forceinline__ void gl_lds16(const bf16* g, bf16* s) {
  __builtin_amdgcn_global_load_lds((__attribute__((address_space(1))) void*)g,
                                   (__attribute__((address_space(3))) void*)s,
                                   16, 0, 0);
}

// ---------------------------------------------------------------------------
// prep (merged): blocks 0..2047 convert x fp32->bf16; blocks 2048..3071
// transpose W [K][N] fp32 -> Wt [z][N][K] bf16 via 64x64 LDS tiles.
// ---------------------------------------------------------------------------
__global__ __launch_bounds__(256) void prep_all(const float* __restrict__ x,
                                                const float* __restrict__ W0,
                                                const float* __restrict__ W1,
                                                const float* __restrict__ W2,
                                                const float* __restrict__ W3,
                                                bf16* __restrict__ xb,
                                                bf16* __restrict__ Wt) {
  __shared__ __align__(16) bf16 Lt[64][68];
  const int bid = blockIdx.x, t = threadIdx.x;
  if (bid < 2048) {
    const size_t i = (size_t)bid * 256 + t;
    const float4 a = ((const float4*)x)[2 * i];
    const float4 b = ((const float4*)x)[2 * i + 1];
    bf16x8 o = {(bf16)a.x, (bf16)a.y, (bf16)a.z, (bf16)a.w,
                (bf16)b.x, (bf16)b.y, (bf16)b.z, (bf16)b.w};
    *(bf16x8*)&xb[i * 8] = o;
    return;
  }
  const int r = bid - 2048;
  const int z = r >> 8, rest = r & 255;
  const float* W = z == 0 ? W0 : z == 1 ? W1 : z == 2 ? W2 : W3;
  const int k0 = (rest & 15) * 64, n0 = (rest >> 4) * 64;
  const int tr = t >> 4, tc = (t & 15) * 4;
#pragma unroll
  for (int p = 0; p < 4; ++p) {
    const int rr = 16 * p + tr;
    const float4 v = *(const float4*)&W[(size_t)(k0 + rr) * D + n0 + tc];
    Lt[tc + 0][rr] = (bf16)v.x;
    Lt[tc + 1][rr] = (bf16)v.y;
    Lt[tc + 2][rr] = (bf16)v.z;
    Lt[tc + 3][rr] = (bf16)v.w;
  }
  __syncthreads();
#pragma unroll
  for (int p = 0; p < 4; ++p) {
    const int n = 16 * p + tr;
    const bf16x4 o = *(const bf16x4*)&Lt[n][tc];
    *(bf16x4*)&Wt[((size_t)z * D + n0 + n) * D + k0 + tc] = o;
  }
}

// ---------------------------------------------------------------------------
// bf16 GEMM, m97 structure: BM=128 x BNT, BK=64, 4 waves, global_load_lds
// staging with XOR-preswizzled source, swizzled b128 frags.
// MODE 0 (BNT=128): fused QKV. Q,K scattered to [B,H,S,Dh] bf16. V blocks
// (bn>=2048) bounce through the (reused) 32KB LDS to emit permuted tile
// images into Vp (r16-verified mapping; coalesced 16B stores both sides).
// MODE 1 (BNT=64): C fp32 row-major [M][D].
// ---------------------------------------------------------------------------
template <int MODE, int BNT>
__global__ __launch_bounds__(256) void gemm_bt(const bf16* __restrict__ A,
                                               const bf16* __restrict__ Bt,
                                               void* __restrict__ Cp,
                                               bf16* __restrict__ Vp) {
  constexpr int K = 1024;
  constexpr int NI = BNT / 32;            // n-frags per wave (4 or 2)
  __shared__ __align__(16) bf16 Sh[(128 + BNT) * 64];
  bf16* As = Sh;
  bf16* Bs = Sh + 128 * 64;

  const int bid = blockIdx.x, nwg = gridDim.x;       // nwg % 8 == 0
  const int lg = (bid & 7) * (nwg >> 3) + (bid >> 3);  // XCD-chunked
  const int bm = (lg & 31) * 128;
  const int bn = (lg >> 5) * BNT;

  const int t = threadIdx.x, l = t & 63, w = t >> 6;
  const int c = l & 15, g = l >> 4, cx = c & 7;
  const int lrow = l >> 3;                  // row within 1KB LDS chunk
  const int srcc = ((l & 7) ^ lrow) << 3;   // pre-swizzled source k-offset
  const int wm = (w >> 1) * 64, wn = (w & 1) * (BNT / 2);

  f32x4 acc[4][NI] = {};

  for (int kt = 0; kt < K / 64; ++kt) {
    const int k0 = kt * 64;
    __syncthreads();  // prior compute done before overwrite
#pragma unroll
    for (int i = 0; i < 4; ++i) {
      const int ci = i * 4 + w;         // 1KB chunk id (16 per 128-row tile)
      const int row = ci * 8 + lrow;    // tile row 0..127
      gl_lds16(A + (size_t)(bm + row) * K + k0 + srcc, As + ci * 512 + l * 8);
    }
#pragma unroll
    for (int i = 0; i < BNT / 32; ++i) {
      const int ci = i * 4 + w;         // BNT/8 chunks of 1KB
      const int row = ci * 8 + lrow;
      gl_lds16(Bt + (size_t)(bn + row) * K + k0 + srcc, Bs + ci * 512 + l * 8);
    }
    __syncthreads();  // drains vmcnt

    bf16x8 af[4][2], bfv[NI][2];
#pragma unroll
    for (int mi = 0; mi < 4; ++mi) {
      const int row = wm + mi * 16 + c;  // row&7 == cx
#pragma unroll
      for (int kh = 0; kh < 2; ++kh)
        af[mi][kh] = *(const bf16x8*)&As[row * 64 + (((kh * 4 + g) ^ cx) << 3)];
    }
#pragma unroll
    for (int ni = 0; ni < NI; ++ni) {
      const int row = wn + ni * 16 + c;
#pragma unroll
      for (int kh = 0; kh < 2; ++kh)
        bfv[ni][kh] = *(const bf16x8*)&Bs[row * 64 + (((kh * 4 + g) ^ cx) << 3)];
    }
#pragma unroll
    for (int mi = 0; mi < 4; ++mi)
#pragma unroll
      for (int ni = 0; ni < NI; ++ni) {
        acc[mi][ni] = mfma16(af[mi][0], bfv[ni][0], acc[mi][ni]);
        acc[mi][ni] = mfma16(af[mi][1], bfv[ni][1], acc[mi][ni]);
      }
  }

  // ---- epilogue (C frag row = 4g+r, col = c; verified mapping) ----
  if (MODE == 0 && bn >= 2048) {
    // V block: bounce through LDS to emit permuted tile images (32KB = 4 tiles)
    __syncthreads();  // all waves done with final fragment reads
#pragma unroll
    for (int mi = 0; mi < 4; ++mi)
#pragma unroll
      for (int ni = 0; ni < NI; ++ni)
#pragma unroll
        for (int r = 0; r < 4; ++r) {
          const int m = bm + wm + mi * 16 + 4 * g + r;
          const int n = bn + wn + ni * 16 + c;
          const int kv = m & 63, d = n & 63;
          const int e = (((kv >> 4) & 1) << 2) | (((kv >> 1) & 1) << 1) | (kv & 1);
          const int vch = ((kv >> 5) << 2) | ((kv >> 2) & 3);
          const int tloc = (((m >> 6) & 1) << 1) | ((n >> 6) & 1);
          Sh[tloc * 4096 + (d << 6) + ((vch ^ (d & 7)) << 3) + e] =
              (bf16)acc[mi][ni][r];
        }
    __syncthreads();
    const int bb2 = bm >> 11, hb = (bn & 1023) >> 6, st0 = (bm & 2047) >> 6;
#pragma unroll
    for (int tl = 0; tl < 4; ++tl) {
      const size_t gt = (size_t)(bb2 * 16 + hb + (tl & 1)) * 32 + st0 + (tl >> 1);
      bf16* dst = Vp + (gt << 12);
      *(bf16x8*)&dst[t * 8] = *(const bf16x8*)&Sh[tl * 4096 + t * 8];
      *(bf16x8*)&dst[2048 + t * 8] = *(const bf16x8*)&Sh[tl * 4096 + 2048 + t * 8];
    }
    return;
  }
#pragma unroll
  for (int mi = 0; mi < 4; ++mi)
#pragma unroll
    for (int ni = 0; ni < NI; ++ni)
#pragma unroll
      for (int r = 0; r < 4; ++r) {
        const int m = bm + wm + mi * 16 + 4 * g + r;
        const int n = bn + wn + ni * 16 + c;
        const float v = acc[mi][ni][r];
        if constexpr (MODE == 0) {
          const int which = n >> 10, nn = n & 1023;
          const int h = nn >> 6, d = nn & 63;
          const int bb = m >> 11, s = m & 2047;
          ((bf16*)Cp)[which * TSZ + ((((size_t)bb * H + h) * S + s) << 6) + d] =
              (bf16)v;
        } else {
          ((float*)Cp)[(size_t)m * D + n] = v;
        }
      }
}

// ---------------------------------------------------------------------------
// Flash attention v20 = r19 (all-DMA staging, uniform pairing (j,31-j),
// single barrier per sync, direct out) with KVBLK=128 SUPER-TILES:
// one sync point covers TWO 64-kv subtiles -> 17 uniform super-iterations
// per block (vs 33), and the two subtiles' QK/softmax/PV chains are
// independent between barriers (subtile 1's MFMAs hide subtile 0's serial
// softmax VALU chain — T15 mechanism). Staging: K = 16-chunk pre-swizzled
// DMA (gemm map); V = identity DMA of 2 contiguous Vp tile images (16KB).
// LDS 64KB (K dbuf 32K + V dbuf 32K) -> 2 blocks/CU (unchanged residency).
// sub=1 skipped when 2it+1 > qt (wave-uniform; only last super-tile).
// ---------------------------------------------------------------------------
__global__ __launch_bounds__(256, 2) void attn20(const bf16* __restrict__ Q,
                                                 const bf16* __restrict__ Kg,
                                                 const bf16* __restrict__ Vp,
                                                 bf16* __restrict__ O) {
  __shared__ __align__(16) bf16 Ks[2 * 8192];   // [parity][128 rows][64]
  __shared__ __align__(16) bf16 Vt[2 * 8192];   // [parity][2 tile images]

  const int bid = blockIdx.x;
  const int bh = bid & 31, j = bid >> 5;          // j in 0..15
  const int t = threadIdx.x, l = t & 63, w = t >> 6;
  const int c = l & 15, g = l >> 4, cx = c & 7;
  const int bb = bh >> 4, h = bh & 15;
  const float SC = 0.18033688011112042f;   // (1/8)*log2(e)
  const float THRS = 44.3614195558365f;    // 8 / SC (defer-max threshold)

  const bf16* Kbase = Kg + (size_t)bh * S * HD;
  const bf16* Vpb = Vp + ((size_t)bh * 32 << 12);  // 32 tiles x 4096 hw

  // DMA maps: 16 chunks of 1KB per 128-row super-tile; thread does 4 chunks
  const int lrow = l >> 3;
  const int srcc = ((l & 7) ^ lrow) << 3;   // K pre-swizzled source offset

  for (int ph = 0; ph < 2; ++ph) {
    const int qt = ph ? (31 - j) : j;
    const int nSup = (qt >> 1) + 1;          // 128-kv super-tiles
    const int qglob = qt * 64 + 16 * w + c;
    const bf16* Qrow = Q + ((size_t)bh * S + qglob) * HD;
    const bf16x8 qf0 = *(const bf16x8*)&Qrow[g * 8];
    const bf16x8 qf1 = *(const bf16x8*)&Qrow[32 + g * 8];

    // ---- phase prologue: protect buffers, then super-tile 0 into par 0 ----
    __builtin_amdgcn_s_barrier();
    __builtin_amdgcn_sched_barrier(0);
#pragma unroll
    for (int i = 0; i < 4; ++i) {
      const int ci = i * 4 + w;
      gl_lds16(Kbase + (size_t)(ci * 8 + lrow) * 64 + srcc, Ks + ci * 512 + l * 8);
      gl_lds16(Vpb + ci * 512 + l * 8, Vt + ci * 512 + l * 8);
    }
    __builtin_amdgcn_sched_barrier(0);

    f32x4 oacc[4] = {};
    float mrun = -1e30f, lrun = 0.f;   // lrun: per-lane partial

    for (int it = 0; it < nSup; ++it) {
      // ---- single sync: my super-tile DMAs drained + all-wave barrier ----
      asm volatile("s_waitcnt vmcnt(0)" ::: "memory");
      __builtin_amdgcn_s_barrier();
      __builtin_amdgcn_sched_barrier(0);

      // ---- issue next super-tile's 8 DMAs into the other parity ----
      if (it + 1 < nSup) {
        const int pb = (it + 1) & 1;
        const bf16* Kn = Kbase + (size_t)(it + 1) * 128 * HD;
        const bf16* Vn = Vpb + ((size_t)(it + 1) << 13);  // 2 tiles = 8192 hw
#pragma unroll
        for (int i = 0; i < 4; ++i) {
          const int ci = i * 4 + w;
          gl_lds16(Kn + (size_t)(ci * 8 + lrow) * 64 + srcc,
                   Ks + pb * 8192 + ci * 512 + l * 8);
          gl_lds16(Vn + ci * 512 + l * 8, Vt + pb * 8192 + ci * 512 + l * 8);
        }
        __builtin_amdgcn_sched_barrier(0);
      }

      const int par = it & 1;
#pragma unroll
      for (int sub = 0; sub < 2; ++sub) {
        const int kte = 2 * it + sub;
        if (kte > qt) break;  // only sub=1 on the last super-tile (even qt)
        const bf16* kbuf = Ks + par * 8192 + sub * 4096;
        const bf16* vbuf = Vt + par * 8192 + sub * 4096;

        // ---- S^T = K Q^T ----
        f32x4 st[4];
        __builtin_amdgcn_s_setprio(1);
#pragma unroll
        for (int ct = 0; ct < 4; ++ct) {
          const int krow = ct * 16 + c;  // krow&7 == cx
          const bf16x8 kf0 = *(const bf16x8*)&kbuf[krow * 64 + ((g ^ cx) << 3)];
          const bf16x8 kf1 = *(const bf16x8*)&kbuf[krow * 64 + (((4 + g) ^ cx) << 3)];
          f32x4 z = {};
          z = mfma16(kf0, qf0, z);
          st[ct] = mfma16(kf1, qf1, z);
        }
        __builtin_amdgcn_s_setprio(0);

        if (kte == qt) {  // causal mask, diagonal subtile only
#pragma unroll
          for (int ct = 0; ct < 4; ++ct)
#pragma unroll
            for (int r = 0; r < 4; ++r)
              if (kte * 64 + ct * 16 + 4 * g + r > qglob) st[ct][r] = -1e30f;
        }

        // ---- in-lane online softmax: tree max, defer-max rescale ----
        float tm[4];
#pragma unroll
        for (int ct = 0; ct < 4; ++ct)
          tm[ct] = fmaxf(fmaxf(st[ct][0], st[ct][1]), fmaxf(st[ct][2], st[ct][3]));
        float mt = fmaxf(fmaxf(tm[0], tm[1]), fmaxf(tm[2], tm[3]));
        mt = fmaxf(mt, __shfl_xor(mt, 16));
        mt = fmaxf(mt, __shfl_xor(mt, 32));
        if (!__all(mt <= mrun + THRS)) {
          const float mnew = fmaxf(mrun, mt);
          const float fac = __builtin_amdgcn_exp2f((mrun - mnew) * SC);
          lrun *= fac;
#pragma unroll
          for (int ct = 0; ct < 4; ++ct)
#pragma unroll
            for (int r = 0; r < 4; ++r) oacc[ct][r] *= fac;
          mrun = mnew;
        }
        float p[4][4];
        float sq[4];
#pragma unroll
        for (int ct = 0; ct < 4; ++ct) {
#pragma unroll
          for (int r = 0; r < 4; ++r)
            p[ct][r] = __builtin_amdgcn_exp2f((st[ct][r] - mrun) * SC);
          sq[ct] = (p[ct][0] + p[ct][1]) + (p[ct][2] + p[ct][3]);
        }
        lrun += (sq[0] + sq[1]) + (sq[2] + sq[3]);

        // ---- P in-register (slot k=8g+jj <-> kv 32h+16(jj>=4)+4g+(jj&3)) ----
        const bf16x8 pa0 = {(bf16)p[0][0], (bf16)p[0][1], (bf16)p[0][2], (bf16)p[0][3],
                            (bf16)p[1][0], (bf16)p[1][1], (bf16)p[1][2], (bf16)p[1][3]};
        const bf16x8 pa1 = {(bf16)p[2][0], (bf16)p[2][1], (bf16)p[2][2], (bf16)p[2][3],
                            (bf16)p[3][0], (bf16)p[3][1], (bf16)p[3][2], (bf16)p[3][3]};

        // ---- O^T += V^T P^T (V^T tile image already kv-permuted) ----
        __builtin_amdgcn_s_setprio(1);
#pragma unroll
        for (int ct = 0; ct < 4; ++ct) {
          const int vrow = ct * 16 + c;
          const bf16x8 vt0 = *(const bf16x8*)&vbuf[vrow * 64 + ((g ^ cx) << 3)];
          const bf16x8 vt1 = *(const bf16x8*)&vbuf[vrow * 64 + (((4 + g) ^ cx) << 3)];
          oacc[ct] = mfma16(vt0, pa0, oacc[ct]);
          oacc[ct] = mfma16(vt1, pa1, oacc[ct]);
        }
        __builtin_amdgcn_s_setprio(0);
      }
    }

    // ---- epilogue: reduce l, normalize, direct bf16 store to [B,S,D] ----
    float lt = lrun;
    lt += __shfl_xor(lt, 16);
    lt += __shfl_xor(lt, 32);
    const float inv = 1.f / lt;
    bf16* Orow = O + ((size_t)bb * S + qglob) * D + h * 64;
#pragma unroll
    for (int ct = 0; ct < 4; ++ct)
#pragma unroll
      for (int pr = 0; pr < 2; ++pr) {
        bf16x2 pk = {(bf16)(oacc[ct][2 * pr] * inv),
                     (bf16)(oacc[ct][2 * pr + 1] * inv)};
        *(bf16x2*)&Orow[ct * 16 + 4 * g + 2 * pr] = pk;
      }
  }
}

// ---------------------------------------------------------------------------
extern "C" void kernel_launch(void* const* d_in, const int* in_sizes, int n_in,
                              void* d_out, int out_size, void* d_ws, size_t ws_size,
                              hipStream_t stream) {
  const float* x  = (const float*)d_in[0];
  const float* Wq = (const float*)d_in[1];
  const float* Wk = (const float*)d_in[2];
  const float* Wv = (const float*)d_in[3];
  const float* Wo = (const float*)d_in[4];
  float* out = (float*)d_out;

  bf16* xb  = (bf16*)d_ws;                       // 4Mi  (8 MB)
  bf16* Wt  = xb + (size_t)B * S * D;            // 4Mi  (8 MB) [4][1024][1024]
  bf16* QKV = Wt + (size_t)4 * D * D;            // 12Mi (24 MB) Q,K used
  bf16* Ab  = QKV + 3 * TSZ;                     // 4Mi  (8 MB) [B*S][D]
  bf16* Vp  = Ab + TSZ;                          // 4Mi  (8 MB) permuted V tiles

  prep_all<<<3072, 256, 0, stream>>>(x, Wq, Wk, Wv, Wo, xb, Wt);
  gemm_bt<0, 128><<<768, 256, 0, stream>>>(xb, Wt, QKV, Vp);         // fused QKV
  attn20<<<512, 256, 0, stream>>>(QKV, QKV + TSZ, Vp, Ab);
  gemm_bt<1, 64><<<512, 256, 0, stream>>>(Ab, Wt + (size_t)3 * D * D, out, nullptr);
}